// Round 4
// baseline (766.367 us; speedup 1.0000x reference)
//
#include <hip/hip_runtime.h>
#include <hip/hip_bf16.h>
#include <stdint.h>

// ConditionalLoRALinear: out = x@W^T + b + mask*(2*(x@A^T)@B^T)
// M=16384, K=4096, N=4096, R=8. bf16 MFMA path.
// R4: m201-style 8-phase schedule adapted: 256x256 tile, BK=64, 2-buffer LDS
//     (128 KiB), 4 phases/K-tile, K-half staging granularity, counted vmcnt(4)
//     once per K-tile (never drain), per-phase {ds_read || stage -> barrier ->
//     lgkmcnt(0) -> setprio -> 16 MFMA -> barrier}. Fragment-major LDS (0-conflict).

typedef __attribute__((ext_vector_type(8))) __bf16 bf16x8;
typedef __attribute__((ext_vector_type(4))) float f32x4;

#define M_DIM 16384
#define K_DIM 4096
#define N_DIM 4096
#define BM 256
#define BN 256
#define BK 64
#define NT2 (K_DIM / BK)   // 64

// ---------------- f32 -> bf16 conversion ----------------
__global__ void cvt_f32_bf16(const float* __restrict__ in, __hip_bfloat16* __restrict__ out, int n8) {
    int i = blockIdx.x * blockDim.x + threadIdx.x;
    int stride = gridDim.x * blockDim.x;
    for (; i < n8; i += stride) {
        const float4* p = (const float4*)(in + (size_t)i * 8);
        float4 v0 = p[0], v1 = p[1];
        bf16x8 o;
        o[0] = (__bf16)v0.x; o[1] = (__bf16)v0.y; o[2] = (__bf16)v0.z; o[3] = (__bf16)v0.w;
        o[4] = (__bf16)v1.x; o[5] = (__bf16)v1.y; o[6] = (__bf16)v1.z; o[7] = (__bf16)v1.w;
        *(bf16x8*)((__hip_bfloat16*)out + (size_t)i * 8) = o;
    }
}

// ---------------- xa[m][r] = 2 * mask(m) * dot(x[m], A[r]) ----------------
__global__ void compute_xa(const __hip_bfloat16* __restrict__ Xb,
                           const int* __restrict__ ids,
                           const float* __restrict__ A,   // [8, K]
                           float* __restrict__ xa) {
    int t = threadIdx.x;
    int r = t & 63;
    int kq = t >> 6;
    int row = blockIdx.x * 64 + r;
    const __hip_bfloat16* xrow = Xb + (size_t)row * K_DIM + kq * 1024;
    float acc[8] = {0.f, 0.f, 0.f, 0.f, 0.f, 0.f, 0.f, 0.f};
    for (int i = 0; i < 128; i++) {
        bf16x8 xv = *(const bf16x8*)(xrow + i * 8);
        int kk = kq * 1024 + i * 8;
#pragma unroll
        for (int rr = 0; rr < 8; rr++) {
            const float* ap = A + rr * K_DIM + kk;
            float4 a0 = *(const float4*)ap;
            float4 a1 = *(const float4*)(ap + 4);
            acc[rr] += (float)xv[0] * a0.x + (float)xv[1] * a0.y + (float)xv[2] * a0.z + (float)xv[3] * a0.w
                     + (float)xv[4] * a1.x + (float)xv[5] * a1.y + (float)xv[6] * a1.z + (float)xv[7] * a1.w;
        }
    }
    __shared__ float red[4][64][8];
#pragma unroll
    for (int rr = 0; rr < 8; rr++) red[kq][r][rr] = acc[rr];
    __syncthreads();
    if (t < 64) {
        int rowg = blockIdx.x * 64 + t;
        float gate = (ids[rowg] == 7) ? 2.0f : 0.0f;
#pragma unroll
        for (int rr = 0; rr < 8; rr++) {
            float s = (red[0][t][rr] + red[1][t][rr]) + (red[2][t][rr] + red[3][t][rr]);
            xa[(size_t)rowg * 8 + rr] = s * gate;
        }
    }
}

// ---------------- main GEMM ----------------
__device__ __forceinline__ void gload_lds16(const void* g, void* l) {
    __builtin_amdgcn_global_load_lds(
        (const __attribute__((address_space(1))) unsigned int*)g,
        (__attribute__((address_space(3))) unsigned int*)l, 16, 0, 0);
}

// LDS per buffer (64 KiB): A 32 KiB then B 32 KiB. Each matrix = 32 chunks of
// 1 KiB, chunk (g, ks) at (g*2+ks)*1024: lane l holds row g*16+(l&15),
// k = ks*32 + (l>>4)*8 .. +8 == the 16x16x32 MFMA fragment for lane l.
// ds_read_b128 at base + lane*16 -> zero bank conflicts; per-lane global source
// implements the permutation (rule #21).
__global__ __launch_bounds__(512, 1) void gemm_bias_lora(
    const __hip_bfloat16* __restrict__ Xb,   // [M, K]
    const __hip_bfloat16* __restrict__ Wb,   // [N, K]
    const float* __restrict__ bias,          // [N]
    const float* __restrict__ xa,            // [M, 8] pre-scaled & gated
    const float* __restrict__ loraB,         // [N, 8]
    float* __restrict__ out) {
    __shared__ char smem[2][65536];          // 128 KiB

    int tid = threadIdx.x;
    int bid = blockIdx.x;
    // XCD-bijective swizzle: nwg = 1024 = 8*128
    int swz = (bid & 7) * 128 + (bid >> 3);
    int n_tile = swz & 15;                   // N/BN = 16
    int m_tile = swz >> 4;                   // M/BM = 64
    int m_base = m_tile * BM, n_base = n_tile * BN;
    int wave = tid >> 6, lane = tid & 63;
    int wr = wave >> 2, wc = wave & 3;       // 2M x 4N wave grid, per-wave 128x64
    int l15 = lane & 15, lhi = lane >> 4;

    f32x4 acc[8][4] = {};

    const char* Abase = (const char*)(Xb + (size_t)m_base * K_DIM);
    const char* Bbase = (const char*)(Wb + (size_t)n_base * K_DIM);

    // stage one 16 KiB unit (= 2 gloads/thread): k-half `ks` of K-tile `kt`,
    // matrix `mat` (0=A,1=B), into buffer `buf`.
    auto stage_unit = [&](int kt, int ks, int mat, int buf) {
        char* base = smem[buf] + mat * 32768;
        const char* gb = mat ? Bbase : Abase;
        size_t kbyte = (size_t)kt * 128 + ks * 64 + lhi * 16;
#pragma unroll
        for (int j = 0; j < 2; j++) {
            int g = j * 8 + wave;
            gload_lds16(gb + (size_t)(g * 16 + l15) * (K_DIM * 2) + kbyte,
                        base + (g * 2 + ks) * 1024 + lane * 16);
        }
    };

    // prologue: tile0 complete (8 loads) + tile1 ks0 (4 loads)
    stage_unit(0, 0, 0, 0); stage_unit(0, 0, 1, 0);
    stage_unit(0, 1, 0, 0); stage_unit(0, 1, 1, 0);
    stage_unit(1, 0, 0, 1); stage_unit(1, 0, 1, 1);
    asm volatile("s_waitcnt vmcnt(4)" ::: "memory");   // tile0 resident; tile1-ks0 in flight
    __builtin_amdgcn_s_barrier();

    for (int t = 0; t < NT2; t++) {
        int cur = t & 1;
        const char* as = smem[cur];
        const char* bs = smem[cur] + 32768;
        bf16x8 af[4], bfr[4];

        // ---- phase 0: quadrant mq=0, ks=0 ----
#pragma unroll
        for (int mi = 0; mi < 4; mi++)
            af[mi] = *(const bf16x8*)(as + ((wr * 8 + mi) * 2 + 0) * 1024 + lane * 16);
#pragma unroll
        for (int ni = 0; ni < 4; ni++)
            bfr[ni] = *(const bf16x8*)(bs + ((wc * 4 + ni) * 2 + 0) * 1024 + lane * 16);
        if (t + 1 < NT2) stage_unit(t + 1, 1, 0, cur ^ 1);   // A ks1 of tile t+1
        __builtin_amdgcn_s_barrier();
        asm volatile("s_waitcnt lgkmcnt(0)" ::: "memory");
        __builtin_amdgcn_sched_barrier(0);
        __builtin_amdgcn_s_setprio(1);
#pragma unroll
        for (int mi = 0; mi < 4; mi++)
#pragma unroll
            for (int ni = 0; ni < 4; ni++)
                acc[mi][ni] = __builtin_amdgcn_mfma_f32_16x16x32_bf16(af[mi], bfr[ni], acc[mi][ni], 0, 0, 0);
        __builtin_amdgcn_s_setprio(0);
        __builtin_amdgcn_s_barrier();

        // ---- phase 1: quadrant mq=1, ks=0 ----
#pragma unroll
        for (int mi = 0; mi < 4; mi++)
            af[mi] = *(const bf16x8*)(as + ((wr * 8 + 4 + mi) * 2 + 0) * 1024 + lane * 16);
        if (t + 1 < NT2) stage_unit(t + 1, 1, 1, cur ^ 1);   // B ks1 of tile t+1
        __builtin_amdgcn_s_barrier();
        asm volatile("s_waitcnt lgkmcnt(0)" ::: "memory");
        __builtin_amdgcn_sched_barrier(0);
        __builtin_amdgcn_s_setprio(1);
#pragma unroll
        for (int mi = 0; mi < 4; mi++)
#pragma unroll
            for (int ni = 0; ni < 4; ni++)
                acc[4 + mi][ni] = __builtin_amdgcn_mfma_f32_16x16x32_bf16(af[mi], bfr[ni], acc[4 + mi][ni], 0, 0, 0);
        __builtin_amdgcn_s_setprio(0);
        __builtin_amdgcn_s_barrier();   // buffer cur ks0 region now free

        // ---- phase 2: quadrant mq=0, ks=1 ----
#pragma unroll
        for (int mi = 0; mi < 4; mi++)
            af[mi] = *(const bf16x8*)(as + ((wr * 8 + mi) * 2 + 1) * 1024 + lane * 16);
#pragma unroll
        for (int ni = 0; ni < 4; ni++)
            bfr[ni] = *(const bf16x8*)(bs + ((wc * 4 + ni) * 2 + 1) * 1024 + lane * 16);
        if (t + 2 < NT2) stage_unit(t + 2, 0, 0, cur);       // A ks0 of tile t+2 -> freed region
        __builtin_amdgcn_s_barrier();
        asm volatile("s_waitcnt lgkmcnt(0)" ::: "memory");
        __builtin_amdgcn_sched_barrier(0);
        __builtin_amdgcn_s_setprio(1);
#pragma unroll
        for (int mi = 0; mi < 4; mi++)
#pragma unroll
            for (int ni = 0; ni < 4; ni++)
                acc[mi][ni] = __builtin_amdgcn_mfma_f32_16x16x32_bf16(af[mi], bfr[ni], acc[mi][ni], 0, 0, 0);
        __builtin_amdgcn_s_setprio(0);
        __builtin_amdgcn_s_barrier();

        // ---- phase 3: quadrant mq=1, ks=1 ----
#pragma unroll
        for (int mi = 0; mi < 4; mi++)
            af[mi] = *(const bf16x8*)(as + ((wr * 8 + 4 + mi) * 2 + 1) * 1024 + lane * 16);
        if (t + 2 < NT2) stage_unit(t + 2, 0, 1, cur);       // B ks0 of tile t+2
        __builtin_amdgcn_s_barrier();
        asm volatile("s_waitcnt lgkmcnt(0)" ::: "memory");
        __builtin_amdgcn_sched_barrier(0);
        __builtin_amdgcn_s_setprio(1);
#pragma unroll
        for (int mi = 0; mi < 4; mi++)
#pragma unroll
            for (int ni = 0; ni < 4; ni++)
                acc[4 + mi][ni] = __builtin_amdgcn_mfma_f32_16x16x32_bf16(af[mi], bfr[ni], acc[4 + mi][ni], 0, 0, 0);
        __builtin_amdgcn_s_setprio(0);
        // counted wait: retire tile t+1's 8 loads; leave tile t+2-ks0's 4 in flight
        if (t < NT2 - 2) asm volatile("s_waitcnt vmcnt(4)" ::: "memory");
        else             asm volatile("s_waitcnt vmcnt(0)" ::: "memory");
        __builtin_amdgcn_s_barrier();
    }

    // epilogue: C/D layout col = lane&15, row = (lane>>4)*4 + reg
    int wrow = m_base + wr * 128;
    int wcol = n_base + wc * 64;
    float bv[4];
    float4 lb0[4], lb1[4];
#pragma unroll
    for (int ni = 0; ni < 4; ni++) {
        int n = wcol + ni * 16 + l15;
        bv[ni] = bias[n];
        lb0[ni] = *(const float4*)(loraB + (size_t)n * 8);
        lb1[ni] = *(const float4*)(loraB + (size_t)n * 8 + 4);
    }
#pragma unroll
    for (int mi = 0; mi < 8; mi++) {
#pragma unroll
        for (int r = 0; r < 4; r++) {
            int m = wrow + mi * 16 + lhi * 4 + r;
            float4 xa0 = *(const float4*)(xa + (size_t)m * 8);
            float4 xa1 = *(const float4*)(xa + (size_t)m * 8 + 4);
#pragma unroll
            for (int ni = 0; ni < 4; ni++) {
                int n = wcol + ni * 16 + l15;
                float lora = xa0.x * lb0[ni].x + xa0.y * lb0[ni].y + xa0.z * lb0[ni].z + xa0.w * lb0[ni].w
                           + xa1.x * lb1[ni].x + xa1.y * lb1[ni].y + xa1.z * lb1[ni].z + xa1.w * lb1[ni].w;
                out[(size_t)m * N_DIM + n] = acc[mi][ni][r] + bv[ni] + lora;
            }
        }
    }
}

// ---------------- fallback (ws too small): correct but slow ----------------
__global__ void fallback_kernel(const float* __restrict__ x, const int* __restrict__ ids,
                                const float* __restrict__ W, const float* __restrict__ b,
                                const float* __restrict__ A, const float* __restrict__ B8,
                                float* __restrict__ out) {
    __shared__ float xs[K_DIM];
    __shared__ float xa_s[8];
    int row = blockIdx.y;
    int t = threadIdx.x;
    const float* xr = x + (size_t)row * K_DIM;
    for (int k = t; k < K_DIM; k += 256) xs[k] = xr[k];
    __syncthreads();
    if (t < 8) {
        float s = 0.f;
        for (int k = 0; k < K_DIM; k++) s += xs[k] * A[t * K_DIM + k];
        xa_s[t] = (ids[row] == 7) ? s * 2.0f : 0.0f;
    }
    __syncthreads();
    int col = blockIdx.x * 256 + t;
    const float* wr = W + (size_t)col * K_DIM;
    float acc = 0.f;
    for (int k = 0; k < K_DIM; k++) acc += xs[k] * wr[k];
    float lora = 0.f;
#pragma unroll
    for (int rr = 0; rr < 8; rr++) lora += xa_s[rr] * B8[col * 8 + rr];
    out[(size_t)row * N_DIM + col] = acc + b[col] + lora;
}

extern "C" void kernel_launch(void* const* d_in, const int* in_sizes, int n_in,
                              void* d_out, int out_size, void* d_ws, size_t ws_size,
                              hipStream_t stream) {
    const float* x   = (const float*)d_in[0];
    const int*   ids = (const int*)d_in[1];
    const float* W   = (const float*)d_in[2];
    const float* b   = (const float*)d_in[3];
    const float* lA  = (const float*)d_in[4];
    const float* lB  = (const float*)d_in[5];
    float* out = (float*)d_out;

    size_t wb_bytes = (size_t)N_DIM * K_DIM * 2;          // 32 MiB
    size_t xb_bytes = (size_t)M_DIM * K_DIM * 2;          // 128 MiB
    size_t xa_bytes = (size_t)M_DIM * 8 * 4;              // 0.5 MiB

    if (ws_size >= wb_bytes + xb_bytes + xa_bytes) {
        __hip_bfloat16* Wb = (__hip_bfloat16*)d_ws;
        __hip_bfloat16* Xb = (__hip_bfloat16*)((char*)d_ws + wb_bytes);
        float* xa = (float*)((char*)d_ws + wb_bytes + xb_bytes);

        cvt_f32_bf16<<<1024, 256, 0, stream>>>(W, Wb, (int)((size_t)N_DIM * K_DIM / 8));
        cvt_f32_bf16<<<2048, 256, 0, stream>>>(x, Xb, (int)((size_t)M_DIM * K_DIM / 8));
        compute_xa<<<M_DIM / 64, 256, 0, stream>>>(Xb, ids, lA, xa);
        gemm_bias_lora<<<(M_DIM / BM) * (N_DIM / BN), 512, 0, stream>>>(Xb, Wb, b, xa, lB, out);
    } else {
        fallback_kernel<<<dim3(N_DIM / 256, M_DIM), 256, 0, stream>>>(x, ids, W, b, lA, lB, out);
    }
}

// Round 5
// 766.109 us; speedup vs baseline: 1.0003x; 1.0003x over previous
//
#include <hip/hip_runtime.h>
#include <hip/hip_bf16.h>
#include <stdint.h>

// ConditionalLoRALinear: out = x@W^T + b + mask*(2*(x@A^T)@B^T)
// M=16384, K=4096, N=4096, R=8. bf16 MFMA path.
// R5: register-level software pipeline. Per phase: issue NEXT quadrant's
// ds_reads (alternate frag set) -> counted lgkmcnt (current quadrant only) ->
// 16 MFMA -> stage -> (counted vmcnt) -> barrier. LDS pipe overlaps matrix
// pipe. 256x256 tile, BK=64, 2-buffer LDS, fragment-major (0-conflict),
// 1 barrier/phase, vmcnt(6) steady (never drain until tail), XCD swizzle.

typedef __attribute__((ext_vector_type(8))) __bf16 bf16x8;
typedef __attribute__((ext_vector_type(4))) float f32x4;

#define M_DIM 16384
#define K_DIM 4096
#define N_DIM 4096
#define BM 256
#define BN 256
#define BK 64
#define NT2 (K_DIM / BK)   // 64

// ---------------- f32 -> bf16 conversion ----------------
__global__ void cvt_f32_bf16(const float* __restrict__ in, __hip_bfloat16* __restrict__ out, int n8) {
    int i = blockIdx.x * blockDim.x + threadIdx.x;
    int stride = gridDim.x * blockDim.x;
    for (; i < n8; i += stride) {
        const float4* p = (const float4*)(in + (size_t)i * 8);
        float4 v0 = p[0], v1 = p[1];
        bf16x8 o;
        o[0] = (__bf16)v0.x; o[1] = (__bf16)v0.y; o[2] = (__bf16)v0.z; o[3] = (__bf16)v0.w;
        o[4] = (__bf16)v1.x; o[5] = (__bf16)v1.y; o[6] = (__bf16)v1.z; o[7] = (__bf16)v1.w;
        *(bf16x8*)((__hip_bfloat16*)out + (size_t)i * 8) = o;
    }
}

// ---------------- xa[m][r] = 2 * mask(m) * dot(x[m], A[r]) ----------------
__global__ void compute_xa(const __hip_bfloat16* __restrict__ Xb,
                           const int* __restrict__ ids,
                           const float* __restrict__ A,   // [8, K]
                           float* __restrict__ xa) {
    int t = threadIdx.x;
    int r = t & 63;
    int kq = t >> 6;
    int row = blockIdx.x * 64 + r;
    const __hip_bfloat16* xrow = Xb + (size_t)row * K_DIM + kq * 1024;
    float acc[8] = {0.f, 0.f, 0.f, 0.f, 0.f, 0.f, 0.f, 0.f};
    for (int i = 0; i < 128; i++) {
        bf16x8 xv = *(const bf16x8*)(xrow + i * 8);
        int kk = kq * 1024 + i * 8;
#pragma unroll
        for (int rr = 0; rr < 8; rr++) {
            const float* ap = A + rr * K_DIM + kk;
            float4 a0 = *(const float4*)ap;
            float4 a1 = *(const float4*)(ap + 4);
            acc[rr] += (float)xv[0] * a0.x + (float)xv[1] * a0.y + (float)xv[2] * a0.z + (float)xv[3] * a0.w
                     + (float)xv[4] * a1.x + (float)xv[5] * a1.y + (float)xv[6] * a1.z + (float)xv[7] * a1.w;
        }
    }
    __shared__ float red[4][64][8];
#pragma unroll
    for (int rr = 0; rr < 8; rr++) red[kq][r][rr] = acc[rr];
    __syncthreads();
    if (t < 64) {
        int rowg = blockIdx.x * 64 + t;
        float gate = (ids[rowg] == 7) ? 2.0f : 0.0f;
#pragma unroll
        for (int rr = 0; rr < 8; rr++) {
            float s = (red[0][t][rr] + red[1][t][rr]) + (red[2][t][rr] + red[3][t][rr]);
            xa[(size_t)rowg * 8 + rr] = s * gate;
        }
    }
}

// ---------------- main GEMM ----------------
__device__ __forceinline__ void gload_lds16(const void* g, void* l) {
    __builtin_amdgcn_global_load_lds(
        (const __attribute__((address_space(1))) unsigned int*)g,
        (__attribute__((address_space(3))) unsigned int*)l, 16, 0, 0);
}

#define LGKM(n)  asm volatile("s_waitcnt lgkmcnt(" #n ")" ::: "memory")
#define VMC(n)   asm volatile("s_waitcnt vmcnt(" #n ")" ::: "memory")
#define SB0()    __builtin_amdgcn_sched_barrier(0)
#define BAR()    __builtin_amdgcn_s_barrier()
#define PRIO(p)  __builtin_amdgcn_s_setprio(p)

// LDS buffer (64 KiB each, x2): A 32 KiB then B 32 KiB; matrix = 32 chunks of
// 1 KiB; chunk (g,ks) at (g*2+ks)*1024; byte lane*16 = row g*16+(lane&15),
// k = ks*32 + (lane>>4)*8 elems == the 16x16x32 MFMA fragment for this lane.
__global__ __launch_bounds__(512, 1) void gemm_bias_lora(
    const __hip_bfloat16* __restrict__ Xb,   // [M, K]
    const __hip_bfloat16* __restrict__ Wb,   // [N, K]
    const float* __restrict__ bias,          // [N]
    const float* __restrict__ xa,            // [M, 8] pre-scaled & gated
    const float* __restrict__ loraB,         // [N, 8]
    float* __restrict__ out) {
    __shared__ char smem[2 * 65536];         // 128 KiB

    int tid = threadIdx.x;
    int bid = blockIdx.x;
    int swz = (bid & 7) * 128 + (bid >> 3);  // XCD-bijective, nwg=1024
    int n_tile = swz & 15;
    int m_tile = swz >> 4;
    int m_base = m_tile * BM, n_base = n_tile * BN;
    int wave = tid >> 6, lane = tid & 63;
    int wr = wave >> 2, wc = wave & 3;       // 2M x 4N waves, per-wave 128x64
    int l15 = lane & 15, lhi = lane >> 4;
    int lane16 = lane * 16;
    unsigned srcLane = (unsigned)l15 * 8192 + (unsigned)lhi * 16;

    f32x4 acc[8][4] = {};

    const char* Abase = (const char*)(Xb + (size_t)m_base * K_DIM);
    const char* Bbase = (const char*)(Wb + (size_t)n_base * K_DIM);

    // stage one 16 KiB unit (2 gloads): k-half ks of K-tile kt, mat (0=A,1=B)
    auto stage_unit = [&](int kt, int ks, int mat, int buf) {
        const char* gb = mat ? Bbase : Abase;
        char* dst = smem + buf * 65536 + mat * 32768 + wave * 2048 + ks * 1024 + lane16;
        unsigned srcU = (unsigned)kt * 128 + (unsigned)ks * 64 + srcLane;
#pragma unroll
        for (int j = 0; j < 2; j++) {
            unsigned g = (unsigned)(wave + j * 8);
            gload_lds16(gb + (size_t)g * 131072 + srcU, dst + j * 16384);
        }
    };

    // fragment register sets (static indexing only)
    bf16x8 afA[4], afB[4], bfA[4], bfB[4];

    // prologue: stage tile0 (A0,B0,A1,B1) + tile1 ks0 (A0,B0) = 12 loads
    stage_unit(0, 0, 0, 0); stage_unit(0, 0, 1, 0);
    stage_unit(0, 1, 0, 0); stage_unit(0, 1, 1, 0);
    stage_unit(1, 0, 0, 1); stage_unit(1, 0, 1, 1);
    VMC(8);                       // retire tile0-ks0 (4 oldest)
    BAR();                        // all waves' ks0(0) landed
    {
        const char* aC = smem + wr * 16384 + lane16;
        const char* bC = smem + 32768 + wc * 8192 + lane16;
#pragma unroll
        for (int mi = 0; mi < 4; mi++) afA[mi] = *(const bf16x8*)(aC + (mi * 2 + 0) * 1024);
#pragma unroll
        for (int ni = 0; ni < 4; ni++) bfA[ni] = *(const bf16x8*)(bC + (ni * 2 + 0) * 1024);
    }

    for (int t = 0; t < NT2; t++) {
        int cur = t & 1;
        const char* aC = smem + cur * 65536 + wr * 16384 + lane16;
        const char* bC = smem + cur * 65536 + 32768 + wc * 8192 + lane16;
        const char* aN = smem + (cur ^ 1) * 65536 + wr * 16384 + lane16;
        const char* bN = smem + (cur ^ 1) * 65536 + 32768 + wc * 8192 + lane16;

        // ---- P0: MFMA q(mq0,ks0) [afA,bfA]; prefetch-read A(mq1,ks0)->afB ----
#pragma unroll
        for (int mi = 0; mi < 4; mi++) afB[mi] = *(const bf16x8*)(aC + ((4 + mi) * 2 + 0) * 1024);
        LGKM(4); SB0();
        PRIO(1);
#pragma unroll
        for (int mi = 0; mi < 4; mi++)
#pragma unroll
            for (int ni = 0; ni < 4; ni++)
                acc[mi][ni] = __builtin_amdgcn_mfma_f32_16x16x32_bf16(afA[mi], bfA[ni], acc[mi][ni], 0, 0, 0);
        PRIO(0);
        if (t + 1 < NT2) stage_unit(t + 1, 1, 0, cur ^ 1);   // A-ks1(t+1)
        if (t < NT2 - 2) { VMC(6); } else { VMC(0); }        // retire ks1(t)
        BAR();

        // ---- P1: MFMA q(mq1,ks0) [afB,bfA]; prefetch-read A(mq0,ks1)->afA, B(ks1)->bfB ----
#pragma unroll
        for (int mi = 0; mi < 4; mi++) afA[mi] = *(const bf16x8*)(aC + (mi * 2 + 1) * 1024);
#pragma unroll
        for (int ni = 0; ni < 4; ni++) bfB[ni] = *(const bf16x8*)(bC + (ni * 2 + 1) * 1024);
        LGKM(8); SB0();
        PRIO(1);
#pragma unroll
        for (int mi = 0; mi < 4; mi++)
#pragma unroll
            for (int ni = 0; ni < 4; ni++)
                acc[4 + mi][ni] = __builtin_amdgcn_mfma_f32_16x16x32_bf16(afB[mi], bfA[ni], acc[4 + mi][ni], 0, 0, 0);
        PRIO(0);
        if (t + 1 < NT2) stage_unit(t + 1, 1, 1, cur ^ 1);   // B-ks1(t+1)
        BAR();

        // ---- P2: MFMA q(mq0,ks1) [afA,bfB]; prefetch-read A(mq1,ks1)->afB ----
#pragma unroll
        for (int mi = 0; mi < 4; mi++) afB[mi] = *(const bf16x8*)(aC + ((4 + mi) * 2 + 1) * 1024);
        LGKM(4); SB0();
        PRIO(1);
#pragma unroll
        for (int mi = 0; mi < 4; mi++)
#pragma unroll
            for (int ni = 0; ni < 4; ni++)
                acc[mi][ni] = __builtin_amdgcn_mfma_f32_16x16x32_bf16(afA[mi], bfB[ni], acc[mi][ni], 0, 0, 0);
        PRIO(0);
        if (t + 2 < NT2) stage_unit(t + 2, 0, 0, cur);       // A-ks0(t+2) -> freed region
        if (t < NT2 - 2) { VMC(6); } else { VMC(0); }        // retire ks0(t+1)
        BAR();

        // ---- P3: MFMA q(mq1,ks1) [afB,bfB]; prefetch-read next tile q(mq0,ks0) ----
        if (t + 1 < NT2) {
#pragma unroll
            for (int mi = 0; mi < 4; mi++) afA[mi] = *(const bf16x8*)(aN + (mi * 2 + 0) * 1024);
#pragma unroll
            for (int ni = 0; ni < 4; ni++) bfA[ni] = *(const bf16x8*)(bN + (ni * 2 + 0) * 1024);
            LGKM(8); SB0();
        } else {
            LGKM(0); SB0();
        }
        PRIO(1);
#pragma unroll
        for (int mi = 0; mi < 4; mi++)
#pragma unroll
            for (int ni = 0; ni < 4; ni++)
                acc[4 + mi][ni] = __builtin_amdgcn_mfma_f32_16x16x32_bf16(afB[mi], bfB[ni], acc[4 + mi][ni], 0, 0, 0);
        PRIO(0);
        if (t + 2 < NT2) stage_unit(t + 2, 0, 1, cur);       // B-ks0(t+2)
        BAR();
    }

    // epilogue: C/D layout col = lane&15, row = (lane>>4)*4 + reg
    int wrow = m_base + wr * 128;
    int wcol = n_base + wc * 64;
    float bv[4];
    float4 lb0[4], lb1[4];
#pragma unroll
    for (int ni = 0; ni < 4; ni++) {
        int n = wcol + ni * 16 + l15;
        bv[ni] = bias[n];
        lb0[ni] = *(const float4*)(loraB + (size_t)n * 8);
        lb1[ni] = *(const float4*)(loraB + (size_t)n * 8 + 4);
    }
#pragma unroll
    for (int mi = 0; mi < 8; mi++) {
#pragma unroll
        for (int r = 0; r < 4; r++) {
            int m = wrow + mi * 16 + lhi * 4 + r;
            float4 xa0 = *(const float4*)(xa + (size_t)m * 8);
            float4 xa1 = *(const float4*)(xa + (size_t)m * 8 + 4);
#pragma unroll
            for (int ni = 0; ni < 4; ni++) {
                int n = wcol + ni * 16 + l15;
                float lora = xa0.x * lb0[ni].x + xa0.y * lb0[ni].y + xa0.z * lb0[ni].z + xa0.w * lb0[ni].w
                           + xa1.x * lb1[ni].x + xa1.y * lb1[ni].y + xa1.z * lb1[ni].z + xa1.w * lb1[ni].w;
                out[(size_t)m * N_DIM + n] = acc[mi][ni][r] + bv[ni] + lora;
            }
        }
    }
}

// ---------------- fallback (ws too small): correct but slow ----------------
__global__ void fallback_kernel(const float* __restrict__ x, const int* __restrict__ ids,
                                const float* __restrict__ W, const float* __restrict__ b,
                                const float* __restrict__ A, const float* __restrict__ B8,
                                float* __restrict__ out) {
    __shared__ float xs[K_DIM];
    __shared__ float xa_s[8];
    int row = blockIdx.y;
    int t = threadIdx.x;
    const float* xr = x + (size_t)row * K_DIM;
    for (int k = t; k < K_DIM; k += 256) xs[k] = xr[k];
    __syncthreads();
    if (t < 8) {
        float s = 0.f;
        for (int k = 0; k < K_DIM; k++) s += xs[k] * A[t * K_DIM + k];
        xa_s[t] = (ids[row] == 7) ? s * 2.0f : 0.0f;
    }
    __syncthreads();
    int col = blockIdx.x * 256 + t;
    const float* wr = W + (size_t)col * K_DIM;
    float acc = 0.f;
    for (int k = 0; k < K_DIM; k++) acc += xs[k] * wr[k];
    float lora = 0.f;
#pragma unroll
    for (int rr = 0; rr < 8; rr++) lora += xa_s[rr] * B8[col * 8 + rr];
    out[(size_t)row * N_DIM + col] = acc + b[col] + lora;
}

extern "C" void kernel_launch(void* const* d_in, const int* in_sizes, int n_in,
                              void* d_out, int out_size, void* d_ws, size_t ws_size,
                              hipStream_t stream) {
    const float* x   = (const float*)d_in[0];
    const int*   ids = (const int*)d_in[1];
    const float* W   = (const float*)d_in[2];
    const float* b   = (const float*)d_in[3];
    const float* lA  = (const float*)d_in[4];
    const float* lB  = (const float*)d_in[5];
    float* out = (float*)d_out;

    size_t wb_bytes = (size_t)N_DIM * K_DIM * 2;          // 32 MiB
    size_t xb_bytes = (size_t)M_DIM * K_DIM * 2;          // 128 MiB
    size_t xa_bytes = (size_t)M_DIM * 8 * 4;              // 0.5 MiB

    if (ws_size >= wb_bytes + xb_bytes + xa_bytes) {
        __hip_bfloat16* Wb = (__hip_bfloat16*)d_ws;
        __hip_bfloat16* Xb = (__hip_bfloat16*)((char*)d_ws + wb_bytes);
        float* xa = (float*)((char*)d_ws + wb_bytes + xb_bytes);

        cvt_f32_bf16<<<1024, 256, 0, stream>>>(W, Wb, (int)((size_t)N_DIM * K_DIM / 8));
        cvt_f32_bf16<<<2048, 256, 0, stream>>>(x, Xb, (int)((size_t)M_DIM * K_DIM / 8));
        compute_xa<<<M_DIM / 64, 256, 0, stream>>>(Xb, ids, lA, xa);
        gemm_bias_lora<<<(M_DIM / BM) * (N_DIM / BN), 512, 0, stream>>>(Xb, Wb, b, xa, lB, out);
    } else {
        fallback_kernel<<<dim3(N_DIM / 256, M_DIM), 256, 0, stream>>>(x, ids, W, b, lA, lB, out);
    }
}

// Round 6
// 704.448 us; speedup vs baseline: 1.0879x; 1.0875x over previous
//
#include <hip/hip_runtime.h>
#include <hip/hip_bf16.h>
#include <stdint.h>

// ConditionalLoRALinear: out = x@W^T + b + mask*(2*(x@A^T)@B^T)
// M=16384, K=4096, N=4096, R=8. bf16 MFMA path.
// R6: row-major LDS [row][128B] with XOR swizzle (chunk p ^= row&7) ->
//     staging is contiguous full-128B-line segments (8 per gload_lds) and
//     ds_read_b128 is bank-balanced. m201-style phases: {reads || stage ->
//     barrier -> lgkmcnt(0) -> setprio -> 16 MFMA -> barrier}, all staging
//     in P0/P1 (>=2-phase lead), one vmcnt(0) per tile. 256x256, BK=64.

typedef __attribute__((ext_vector_type(8))) __bf16 bf16x8;
typedef __attribute__((ext_vector_type(4))) float f32x4;

#define M_DIM 16384
#define K_DIM 4096
#define N_DIM 4096
#define BM 256
#define BN 256
#define BK 64
#define NT2 (K_DIM / BK)   // 64

// ---------------- f32 -> bf16 conversion ----------------
__global__ void cvt_f32_bf16(const float* __restrict__ in, __hip_bfloat16* __restrict__ out, int n8) {
    int i = blockIdx.x * blockDim.x + threadIdx.x;
    int stride = gridDim.x * blockDim.x;
    for (; i < n8; i += stride) {
        const float4* p = (const float4*)(in + (size_t)i * 8);
        float4 v0 = p[0], v1 = p[1];
        bf16x8 o;
        o[0] = (__bf16)v0.x; o[1] = (__bf16)v0.y; o[2] = (__bf16)v0.z; o[3] = (__bf16)v0.w;
        o[4] = (__bf16)v1.x; o[5] = (__bf16)v1.y; o[6] = (__bf16)v1.z; o[7] = (__bf16)v1.w;
        *(bf16x8*)((__hip_bfloat16*)out + (size_t)i * 8) = o;
    }
}

// ---------------- xa[m][r] = 2 * mask(m) * dot(x[m], A[r]) ----------------
__global__ void compute_xa(const __hip_bfloat16* __restrict__ Xb,
                           const int* __restrict__ ids,
                           const float* __restrict__ A,   // [8, K]
                           float* __restrict__ xa) {
    int t = threadIdx.x;
    int r = t & 63;
    int kq = t >> 6;
    int row = blockIdx.x * 64 + r;
    const __hip_bfloat16* xrow = Xb + (size_t)row * K_DIM + kq * 1024;
    float acc[8] = {0.f, 0.f, 0.f, 0.f, 0.f, 0.f, 0.f, 0.f};
    for (int i = 0; i < 128; i++) {
        bf16x8 xv = *(const bf16x8*)(xrow + i * 8);
        int kk = kq * 1024 + i * 8;
#pragma unroll
        for (int rr = 0; rr < 8; rr++) {
            const float* ap = A + rr * K_DIM + kk;
            float4 a0 = *(const float4*)ap;
            float4 a1 = *(const float4*)(ap + 4);
            acc[rr] += (float)xv[0] * a0.x + (float)xv[1] * a0.y + (float)xv[2] * a0.z + (float)xv[3] * a0.w
                     + (float)xv[4] * a1.x + (float)xv[5] * a1.y + (float)xv[6] * a1.z + (float)xv[7] * a1.w;
        }
    }
    __shared__ float red[4][64][8];
#pragma unroll
    for (int rr = 0; rr < 8; rr++) red[kq][r][rr] = acc[rr];
    __syncthreads();
    if (t < 64) {
        int rowg = blockIdx.x * 64 + t;
        float gate = (ids[rowg] == 7) ? 2.0f : 0.0f;
#pragma unroll
        for (int rr = 0; rr < 8; rr++) {
            float s = (red[0][t][rr] + red[1][t][rr]) + (red[2][t][rr] + red[3][t][rr]);
            xa[(size_t)rowg * 8 + rr] = s * gate;
        }
    }
}

// ---------------- main GEMM ----------------
__device__ __forceinline__ void gload_lds16(const void* g, void* l) {
    __builtin_amdgcn_global_load_lds(
        (const __attribute__((address_space(1))) unsigned int*)g,
        (__attribute__((address_space(3))) unsigned int*)l, 16, 0, 0);
}

#define LGKM0()  asm volatile("s_waitcnt lgkmcnt(0)" ::: "memory")
#define VMC0()   asm volatile("s_waitcnt vmcnt(0)" ::: "memory")
#define BAR()    __builtin_amdgcn_s_barrier()
#define PRIO(p)  __builtin_amdgcn_s_setprio(p)

// LDS per buffer (64 KiB): A (256 rows x 128 B) then B (256 rows x 128 B).
// Byte (row, p*16) holds k-chunk c = p ^ (row&7) of that row's K-tile slice
// (16 B chunks, 8 per row). Staging: linear dest, inverse-swizzled global
// source (full 128 B line segments, coalesced). Read: swizzled chunk index,
// 32 B/bank balanced per ds_read_b128.
__global__ __launch_bounds__(512, 1) void gemm_bias_lora(
    const __hip_bfloat16* __restrict__ Xb,   // [M, K]
    const __hip_bfloat16* __restrict__ Wb,   // [N, K]
    const float* __restrict__ bias,          // [N]
    const float* __restrict__ xa,            // [M, 8] pre-scaled & gated
    const float* __restrict__ loraB,         // [N, 8]
    float* __restrict__ out) {
    __shared__ char smem[2 * 65536];         // 128 KiB

    int tid = threadIdx.x;
    int bid = blockIdx.x;
    int swz = (bid & 7) * 128 + (bid >> 3);  // XCD-bijective, nwg=1024
    int n_tile = swz & 15;
    int m_tile = swz >> 4;
    int m_base = m_tile * BM, n_base = n_tile * BN;
    int wave = tid >> 6, lane = tid & 63;
    int wr = wave >> 2, wc = wave & 3;       // 2M x 4N waves, per-wave 128x64
    int l15 = lane & 15, lhi = lane >> 4;
    int l8 = lane >> 3;
    int cx = (((lane & 7) ^ (l8 & 7)) * 16); // staging source chunk (inverse swizzle)
    int pswz0 = ((lhi)     ^ (l15 & 7)) * 16; // read chunk byte, ks=0
    int pswz1 = ((4 + lhi) ^ (l15 & 7)) * 16; // read chunk byte, ks=1

    f32x4 acc[8][4] = {};

    const char* Abase = (const char*)(Xb + (size_t)m_base * K_DIM);
    const char* Bbase = (const char*)(Wb + (size_t)n_base * K_DIM);

    // stage one 16 KiB unit (2 gloads/thread): matrix mat (0=A,1=B), row-half h
    auto stage_unit = [&](int kt, int mat, int h, int buf) {
        const char* gb = mat ? Bbase : Abase;
        char* dstb = smem + buf * 65536 + mat * 32768 + (h * 128 + wave * 16) * 128 + lane * 16;
        size_t kb = (size_t)kt * 128 + cx;
#pragma unroll
        for (int j = 0; j < 2; j++) {
            int grow = h * 128 + wave * 16 + j * 8 + l8;
            gload_lds16(gb + (size_t)grow * (K_DIM * 2) + kb, dstb + j * 1024);
        }
    };

    // prologue: stage tile0 (4 units)
    stage_unit(0, 0, 0, 0); stage_unit(0, 1, 0, 0);
    stage_unit(0, 0, 1, 0); stage_unit(0, 1, 1, 0);
    VMC0();
    BAR();

    for (int t = 0; t < NT2; t++) {
        int cur = t & 1;
        // A row base for this wave/lane: rows wr*128 + (mq*4+mi)*16 + l15
        const char* aR = smem + cur * 65536 + ((size_t)(wr * 128 + l15)) * 128;
        const char* bR = smem + cur * 65536 + 32768 + ((size_t)(wc * 64 + l15)) * 128;
        bf16x8 af[4], bfr[4];

        // ---- P0: quadrant (mq0, ks0) ----
#pragma unroll
        for (int mi = 0; mi < 4; mi++) af[mi] = *(const bf16x8*)(aR + mi * 2048 + pswz0);
#pragma unroll
        for (int ni = 0; ni < 4; ni++) bfr[ni] = *(const bf16x8*)(bR + ni * 2048 + pswz0);
        if (t + 1 < NT2) { stage_unit(t + 1, 0, 0, cur ^ 1); stage_unit(t + 1, 1, 0, cur ^ 1); }
        BAR();
        LGKM0();
        PRIO(1);
#pragma unroll
        for (int mi = 0; mi < 4; mi++)
#pragma unroll
            for (int ni = 0; ni < 4; ni++)
                acc[mi][ni] = __builtin_amdgcn_mfma_f32_16x16x32_bf16(af[mi], bfr[ni], acc[mi][ni], 0, 0, 0);
        PRIO(0);
        BAR();

        // ---- P1: quadrant (mq1, ks0) ----
#pragma unroll
        for (int mi = 0; mi < 4; mi++) af[mi] = *(const bf16x8*)(aR + (4 + mi) * 2048 + pswz0);
        if (t + 1 < NT2) { stage_unit(t + 1, 0, 1, cur ^ 1); stage_unit(t + 1, 1, 1, cur ^ 1); }
        BAR();
        LGKM0();
        PRIO(1);
#pragma unroll
        for (int mi = 0; mi < 4; mi++)
#pragma unroll
            for (int ni = 0; ni < 4; ni++)
                acc[4 + mi][ni] = __builtin_amdgcn_mfma_f32_16x16x32_bf16(af[mi], bfr[ni], acc[4 + mi][ni], 0, 0, 0);
        PRIO(0);
        BAR();

        // ---- P2: quadrant (mq0, ks1) ----
#pragma unroll
        for (int mi = 0; mi < 4; mi++) af[mi] = *(const bf16x8*)(aR + mi * 2048 + pswz1);
#pragma unroll
        for (int ni = 0; ni < 4; ni++) bfr[ni] = *(const bf16x8*)(bR + ni * 2048 + pswz1);
        BAR();
        LGKM0();
        PRIO(1);
#pragma unroll
        for (int mi = 0; mi < 4; mi++)
#pragma unroll
            for (int ni = 0; ni < 4; ni++)
                acc[mi][ni] = __builtin_amdgcn_mfma_f32_16x16x32_bf16(af[mi], bfr[ni], acc[mi][ni], 0, 0, 0);
        PRIO(0);
        BAR();

        // ---- P3: quadrant (mq1, ks1) ----
#pragma unroll
        for (int mi = 0; mi < 4; mi++) af[mi] = *(const bf16x8*)(aR + (4 + mi) * 2048 + pswz1);
        BAR();
        LGKM0();
        PRIO(1);
#pragma unroll
        for (int mi = 0; mi < 4; mi++)
#pragma unroll
            for (int ni = 0; ni < 4; ni++)
                acc[4 + mi][ni] = __builtin_amdgcn_mfma_f32_16x16x32_bf16(af[mi], bfr[ni], acc[4 + mi][ni], 0, 0, 0);
        PRIO(0);
        // next tile's 8 loads were issued >=2 phases ago -> this is a cheap wait
        VMC0();
        BAR();
    }

    // epilogue: C/D layout col = lane&15, row = (lane>>4)*4 + reg
    int wrow = m_base + wr * 128;
    int wcol = n_base + wc * 64;
    float bv[4];
    float4 lb0[4], lb1[4];
#pragma unroll
    for (int ni = 0; ni < 4; ni++) {
        int n = wcol + ni * 16 + l15;
        bv[ni] = bias[n];
        lb0[ni] = *(const float4*)(loraB + (size_t)n * 8);
        lb1[ni] = *(const float4*)(loraB + (size_t)n * 8 + 4);
    }
#pragma unroll
    for (int mi = 0; mi < 8; mi++) {
#pragma unroll
        for (int r = 0; r < 4; r++) {
            int m = wrow + mi * 16 + lhi * 4 + r;
            float4 xa0 = *(const float4*)(xa + (size_t)m * 8);
            float4 xa1 = *(const float4*)(xa + (size_t)m * 8 + 4);
#pragma unroll
            for (int ni = 0; ni < 4; ni++) {
                int n = wcol + ni * 16 + l15;
                float lora = xa0.x * lb0[ni].x + xa0.y * lb0[ni].y + xa0.z * lb0[ni].z + xa0.w * lb0[ni].w
                           + xa1.x * lb1[ni].x + xa1.y * lb1[ni].y + xa1.z * lb1[ni].z + xa1.w * lb1[ni].w;
                out[(size_t)m * N_DIM + n] = acc[mi][ni][r] + bv[ni] + lora;
            }
        }
    }
}

// ---------------- fallback (ws too small): correct but slow ----------------
__global__ void fallback_kernel(const float* __restrict__ x, const int* __restrict__ ids,
                                const float* __restrict__ W, const float* __restrict__ b,
                                const float* __restrict__ A, const float* __restrict__ B8,
                                float* __restrict__ out) {
    __shared__ float xs[K_DIM];
    __shared__ float xa_s[8];
    int row = blockIdx.y;
    int t = threadIdx.x;
    const float* xr = x + (size_t)row * K_DIM;
    for (int k = t; k < K_DIM; k += 256) xs[k] = xr[k];
    __syncthreads();
    if (t < 8) {
        float s = 0.f;
        for (int k = 0; k < K_DIM; k++) s += xs[k] * A[t * K_DIM + k];
        xa_s[t] = (ids[row] == 7) ? s * 2.0f : 0.0f;
    }
    __syncthreads();
    int col = blockIdx.x * 256 + t;
    const float* wr = W + (size_t)col * K_DIM;
    float acc = 0.f;
    for (int k = 0; k < K_DIM; k++) acc += xs[k] * wr[k];
    float lora = 0.f;
#pragma unroll
    for (int rr = 0; rr < 8; rr++) lora += xa_s[rr] * B8[col * 8 + rr];
    out[(size_t)row * N_DIM + col] = acc + b[col] + lora;
}

extern "C" void kernel_launch(void* const* d_in, const int* in_sizes, int n_in,
                              void* d_out, int out_size, void* d_ws, size_t ws_size,
                              hipStream_t stream) {
    const float* x   = (const float*)d_in[0];
    const int*   ids = (const int*)d_in[1];
    const float* W   = (const float*)d_in[2];
    const float* b   = (const float*)d_in[3];
    const float* lA  = (const float*)d_in[4];
    const float* lB  = (const float*)d_in[5];
    float* out = (float*)d_out;

    size_t wb_bytes = (size_t)N_DIM * K_DIM * 2;          // 32 MiB
    size_t xb_bytes = (size_t)M_DIM * K_DIM * 2;          // 128 MiB
    size_t xa_bytes = (size_t)M_DIM * 8 * 4;              // 0.5 MiB

    if (ws_size >= wb_bytes + xb_bytes + xa_bytes) {
        __hip_bfloat16* Wb = (__hip_bfloat16*)d_ws;
        __hip_bfloat16* Xb = (__hip_bfloat16*)((char*)d_ws + wb_bytes);
        float* xa = (float*)((char*)d_ws + wb_bytes + xb_bytes);

        cvt_f32_bf16<<<1024, 256, 0, stream>>>(W, Wb, (int)((size_t)N_DIM * K_DIM / 8));
        cvt_f32_bf16<<<2048, 256, 0, stream>>>(x, Xb, (int)((size_t)M_DIM * K_DIM / 8));
        compute_xa<<<M_DIM / 64, 256, 0, stream>>>(Xb, ids, lA, xa);
        gemm_bias_lora<<<(M_DIM / BM) * (N_DIM / BN), 512, 0, stream>>>(Xb, Wb, b, xa, lB, out);
    } else {
        fallback_kernel<<<dim3(N_DIM / 256, M_DIM), 256, 0, stream>>>(x, ids, W, b, lA, lB, out);
    }
}

// Round 7
// 672.130 us; speedup vs baseline: 1.1402x; 1.0481x over previous
//
#include <hip/hip_runtime.h>
#include <hip/hip_bf16.h>
#include <stdint.h>

// ConditionalLoRALinear: out = x@W^T + b + mask*(2*(x@A^T)@B^T)
// M=16384, K=4096, N=4096, R=8. bf16 MFMA path.
// R7: R6 staging (row-major + XOR swizzle, 128B-line coalesced) + TRUE counted
//     vmcnt pipeline: A split into two 16KiB mq-units (rows reordered so each
//     unit is contiguous in LDS), 1 unit staged per phase, vmcnt(4) at end-P0
//     and end-P3 only (never drain in main loop). Stage->required-resident lag
//     >= 2 phases. 256x256, BK=64, 2 buffers, 8 waves.

typedef __attribute__((ext_vector_type(8))) __bf16 bf16x8;
typedef __attribute__((ext_vector_type(4))) float f32x4;

#define M_DIM 16384
#define K_DIM 4096
#define N_DIM 4096
#define BM 256
#define BN 256
#define BK 64
#define NT2 (K_DIM / BK)   // 64

// ---------------- f32 -> bf16 conversion ----------------
__global__ void cvt_f32_bf16(const float* __restrict__ in, __hip_bfloat16* __restrict__ out, int n8) {
    int i = blockIdx.x * blockDim.x + threadIdx.x;
    int stride = gridDim.x * blockDim.x;
    for (; i < n8; i += stride) {
        const float4* p = (const float4*)(in + (size_t)i * 8);
        float4 v0 = p[0], v1 = p[1];
        bf16x8 o;
        o[0] = (__bf16)v0.x; o[1] = (__bf16)v0.y; o[2] = (__bf16)v0.z; o[3] = (__bf16)v0.w;
        o[4] = (__bf16)v1.x; o[5] = (__bf16)v1.y; o[6] = (__bf16)v1.z; o[7] = (__bf16)v1.w;
        *(bf16x8*)((__hip_bfloat16*)out + (size_t)i * 8) = o;
    }
}

// ---------------- xa[m][r] = 2 * mask(m) * dot(x[m], A[r]) ----------------
__global__ void compute_xa(const __hip_bfloat16* __restrict__ Xb,
                           const int* __restrict__ ids,
                           const float* __restrict__ A,   // [8, K]
                           float* __restrict__ xa) {
    int t = threadIdx.x;
    int r = t & 63;
    int kq = t >> 6;
    int row = blockIdx.x * 64 + r;
    const __hip_bfloat16* xrow = Xb + (size_t)row * K_DIM + kq * 1024;
    float acc[8] = {0.f, 0.f, 0.f, 0.f, 0.f, 0.f, 0.f, 0.f};
    for (int i = 0; i < 128; i++) {
        bf16x8 xv = *(const bf16x8*)(xrow + i * 8);
        int kk = kq * 1024 + i * 8;
#pragma unroll
        for (int rr = 0; rr < 8; rr++) {
            const float* ap = A + rr * K_DIM + kk;
            float4 a0 = *(const float4*)ap;
            float4 a1 = *(const float4*)(ap + 4);
            acc[rr] += (float)xv[0] * a0.x + (float)xv[1] * a0.y + (float)xv[2] * a0.z + (float)xv[3] * a0.w
                     + (float)xv[4] * a1.x + (float)xv[5] * a1.y + (float)xv[6] * a1.z + (float)xv[7] * a1.w;
        }
    }
    __shared__ float red[4][64][8];
#pragma unroll
    for (int rr = 0; rr < 8; rr++) red[kq][r][rr] = acc[rr];
    __syncthreads();
    if (t < 64) {
        int rowg = blockIdx.x * 64 + t;
        float gate = (ids[rowg] == 7) ? 2.0f : 0.0f;
#pragma unroll
        for (int rr = 0; rr < 8; rr++) {
            float s = (red[0][t][rr] + red[1][t][rr]) + (red[2][t][rr] + red[3][t][rr]);
            xa[(size_t)rowg * 8 + rr] = s * gate;
        }
    }
}

// ---------------- main GEMM ----------------
__device__ __forceinline__ void gload_lds16(const void* g, void* l) {
    __builtin_amdgcn_global_load_lds(
        (const __attribute__((address_space(1))) unsigned int*)g,
        (__attribute__((address_space(3))) unsigned int*)l, 16, 0, 0);
}

#define LGKM0()  asm volatile("s_waitcnt lgkmcnt(0)" ::: "memory")
#define VMC4()   asm volatile("s_waitcnt vmcnt(4)" ::: "memory")
#define VMC0()   asm volatile("s_waitcnt vmcnt(0)" ::: "memory")
#define BAR()    __builtin_amdgcn_s_barrier()
#define PRIO(p)  __builtin_amdgcn_s_setprio(p)

// LDS per buffer (64 KiB):
//   A (32 KiB) = 2 units of 16 KiB. Unit mq holds, contiguously, the 128 rows
//   read by the mq-phases: [wr=0: global rows mq*64..+63][wr=1: 128+mq*64..+63].
//   B (32 KiB) = row-major [256][128B] (rows 0-127 = unit B-h0, 128-255 = B-h1).
// Within any row: 8 chunks of 16 B, stored at position p = chunk ^ (row&7)
// (XOR swizzle; staging writes linear dest + inverse-swizzled global source).
__global__ __launch_bounds__(512, 1) void gemm_bias_lora(
    const __hip_bfloat16* __restrict__ Xb,   // [M, K]
    const __hip_bfloat16* __restrict__ Wb,   // [N, K]
    const float* __restrict__ bias,          // [N]
    const float* __restrict__ xa,            // [M, 8] pre-scaled & gated
    const float* __restrict__ loraB,         // [N, 8]
    float* __restrict__ out) {
    __shared__ char smem[2 * 65536];         // 128 KiB

    int tid = threadIdx.x;
    int bid = blockIdx.x;
    int swz = (bid & 7) * 128 + (bid >> 3);  // XCD-bijective, nwg=1024
    int n_tile = swz & 15;
    int m_tile = swz >> 4;
    int m_base = m_tile * BM, n_base = n_tile * BN;
    int wave = tid >> 6, lane = tid & 63;
    int wr = wave >> 2, wc = wave & 3;       // 2M x 4N waves, per-wave 128x64
    int l15 = lane & 15, lhi = lane >> 4;
    int l8 = lane >> 3;
    int cx = ((lane & 7) ^ l8) * 16;          // staging source chunk (inverse swizzle)
    int pswz0 = ((lhi)     ^ (l15 & 7)) * 16; // read chunk byte, ks=0
    int pswz1 = ((4 + lhi) ^ (l15 & 7)) * 16; // read chunk byte, ks=1

    f32x4 acc[8][4] = {};

    const char* Abase = (const char*)(Xb + (size_t)m_base * K_DIM);
    const char* Bbase = (const char*)(Wb + (size_t)n_base * K_DIM);

    // stage unit A-mq (16 KiB, 2 gloads/thread) of K-tile kt into buffer buf
    auto stage_A = [&](int kt, int mq, int buf) {
        char* ub = smem + buf * 65536 + mq * 16384;
#pragma unroll
        for (int j = 0; j < 2; j++) {
            int rg = wave * 2 + j;                 // row-group 0..15 within unit
            int rl = rg * 8 + l8;                  // unit-local row 0..127
            int g = (rl < 64) ? (mq * 64 + rl) : (128 + mq * 64 + (rl - 64));
            gload_lds16(Abase + (size_t)g * (K_DIM * 2) + (size_t)kt * 128 + cx,
                        ub + rg * 1024 + lane * 16);
        }
    };
    // stage unit B-h (16 KiB): rows h*128 .. h*128+127, row-major
    auto stage_B = [&](int kt, int h, int buf) {
        char* ub = smem + buf * 65536 + 32768 + h * 16384;
#pragma unroll
        for (int j = 0; j < 2; j++) {
            int rg = wave * 2 + j;
            int row = h * 128 + rg * 8 + l8;
            gload_lds16(Bbase + (size_t)row * (K_DIM * 2) + (size_t)kt * 128 + cx,
                        ub + rg * 1024 + lane * 16);
        }
    };

    // prologue: tile0 all 4 units + A-m0(1) (its steady-state slot is P3(t-1))
    stage_A(0, 0, 0); stage_B(0, 0, 0); stage_B(0, 1, 0); stage_A(0, 1, 0);
    stage_A(1, 0, 1);
    VMC0();
    BAR();

    for (int t = 0; t < NT2; t++) {
        int cur = t & 1, nb = cur ^ 1;
        const char* aU0 = smem + cur * 65536 + (wr * 64 + l15) * 128;          // A unit 0
        const char* aU1 = aU0 + 16384;                                          // A unit 1
        const char* bRb = smem + cur * 65536 + 32768 + (wc * 64 + l15) * 128;  // B rows
        bf16x8 af[4], bfr[4];

        // ---- P0: (mq0, ks0) ----
#pragma unroll
        for (int mi = 0; mi < 4; mi++) af[mi] = *(const bf16x8*)(aU0 + mi * 2048 + pswz0);
#pragma unroll
        for (int ni = 0; ni < 4; ni++) bfr[ni] = *(const bf16x8*)(bRb + ni * 2048 + pswz0);
        if (t + 1 < NT2) stage_B(t + 1, 0, nb);
        BAR();
        LGKM0();
        PRIO(1);
#pragma unroll
        for (int mi = 0; mi < 4; mi++)
#pragma unroll
            for (int ni = 0; ni < 4; ni++)
                acc[mi][ni] = __builtin_amdgcn_mfma_f32_16x16x32_bf16(af[mi], bfr[ni], acc[mi][ni], 0, 0, 0);
        PRIO(0);
        VMC4();   // retire A-m1(t) (read next phase); leave {A-m0(t+1), B-h0(t+1)}
        BAR();

        // ---- P1: (mq1, ks0) ----
#pragma unroll
        for (int mi = 0; mi < 4; mi++) af[mi] = *(const bf16x8*)(aU1 + mi * 2048 + pswz0);
        if (t + 1 < NT2) stage_B(t + 1, 1, nb);
        BAR();
        LGKM0();
        PRIO(1);
#pragma unroll
        for (int mi = 0; mi < 4; mi++)
#pragma unroll
            for (int ni = 0; ni < 4; ni++)
                acc[4 + mi][ni] = __builtin_amdgcn_mfma_f32_16x16x32_bf16(af[mi], bfr[ni], acc[4 + mi][ni], 0, 0, 0);
        PRIO(0);
        BAR();

        // ---- P2: (mq0, ks1) ----
#pragma unroll
        for (int mi = 0; mi < 4; mi++) af[mi] = *(const bf16x8*)(aU0 + mi * 2048 + pswz1);
#pragma unroll
        for (int ni = 0; ni < 4; ni++) bfr[ni] = *(const bf16x8*)(bRb + ni * 2048 + pswz1);
        if (t + 1 < NT2) stage_A(t + 1, 1, nb);
        BAR();
        LGKM0();
        PRIO(1);
#pragma unroll
        for (int mi = 0; mi < 4; mi++)
#pragma unroll
            for (int ni = 0; ni < 4; ni++)
                acc[mi][ni] = __builtin_amdgcn_mfma_f32_16x16x32_bf16(af[mi], bfr[ni], acc[mi][ni], 0, 0, 0);
        PRIO(0);
        BAR();

        // ---- P3: (mq1, ks1) ----
#pragma unroll
        for (int mi = 0; mi < 4; mi++) af[mi] = *(const bf16x8*)(aU1 + mi * 2048 + pswz1);
        if (t + 2 < NT2) stage_A(t + 2, 0, cur);   // current buf's A-m0: freed after P2
        BAR();
        LGKM0();
        PRIO(1);
#pragma unroll
        for (int mi = 0; mi < 4; mi++)
#pragma unroll
            for (int ni = 0; ni < 4; ni++)
                acc[4 + mi][ni] = __builtin_amdgcn_mfma_f32_16x16x32_bf16(af[mi], bfr[ni], acc[4 + mi][ni], 0, 0, 0);
        PRIO(0);
        // retire A-m0(t+1), B-h0(t+1), B-h1(t+1); leave {A-m1(t+1), A-m0(t+2)}
        if (t < NT2 - 2) { VMC4(); } else { VMC0(); }
        BAR();
    }

    // epilogue: C/D layout col = lane&15, row = (lane>>4)*4 + reg
    int wrow = m_base + wr * 128;
    int wcol = n_base + wc * 64;
    float bv[4];
    float4 lb0[4], lb1[4];
#pragma unroll
    for (int ni = 0; ni < 4; ni++) {
        int n = wcol + ni * 16 + l15;
        bv[ni] = bias[n];
        lb0[ni] = *(const float4*)(loraB + (size_t)n * 8);
        lb1[ni] = *(const float4*)(loraB + (size_t)n * 8 + 4);
    }
#pragma unroll
    for (int mi = 0; mi < 8; mi++) {
#pragma unroll
        for (int r = 0; r < 4; r++) {
            int m = wrow + mi * 16 + lhi * 4 + r;
            float4 xa0 = *(const float4*)(xa + (size_t)m * 8);
            float4 xa1 = *(const float4*)(xa + (size_t)m * 8 + 4);
#pragma unroll
            for (int ni = 0; ni < 4; ni++) {
                int n = wcol + ni * 16 + l15;
                float lora = xa0.x * lb0[ni].x + xa0.y * lb0[ni].y + xa0.z * lb0[ni].z + xa0.w * lb0[ni].w
                           + xa1.x * lb1[ni].x + xa1.y * lb1[ni].y + xa1.z * lb1[ni].z + xa1.w * lb1[ni].w;
                out[(size_t)m * N_DIM + n] = acc[mi][ni][r] + bv[ni] + lora;
            }
        }
    }
}

// ---------------- fallback (ws too small): correct but slow ----------------
__global__ void fallback_kernel(const float* __restrict__ x, const int* __restrict__ ids,
                                const float* __restrict__ W, const float* __restrict__ b,
                                const float* __restrict__ A, const float* __restrict__ B8,
                                float* __restrict__ out) {
    __shared__ float xs[K_DIM];
    __shared__ float xa_s[8];
    int row = blockIdx.y;
    int t = threadIdx.x;
    const float* xr = x + (size_t)row * K_DIM;
    for (int k = t; k < K_DIM; k += 256) xs[k] = xr[k];
    __syncthreads();
    if (t < 8) {
        float s = 0.f;
        for (int k = 0; k < K_DIM; k++) s += xs[k] * A[t * K_DIM + k];
        xa_s[t] = (ids[row] == 7) ? s * 2.0f : 0.0f;
    }
    __syncthreads();
    int col = blockIdx.x * 256 + t;
    const float* wr = W + (size_t)col * K_DIM;
    float acc = 0.f;
    for (int k = 0; k < K_DIM; k++) acc += xs[k] * wr[k];
    float lora = 0.f;
#pragma unroll
    for (int rr = 0; rr < 8; rr++) lora += xa_s[rr] * B8[col * 8 + rr];
    out[(size_t)row * N_DIM + col] = acc + b[col] + lora;
}

extern "C" void kernel_launch(void* const* d_in, const int* in_sizes, int n_in,
                              void* d_out, int out_size, void* d_ws, size_t ws_size,
                              hipStream_t stream) {
    const float* x   = (const float*)d_in[0];
    const int*   ids = (const int*)d_in[1];
    const float* W   = (const float*)d_in[2];
    const float* b   = (const float*)d_in[3];
    const float* lA  = (const float*)d_in[4];
    const float* lB  = (const float*)d_in[5];
    float* out = (float*)d_out;

    size_t wb_bytes = (size_t)N_DIM * K_DIM * 2;          // 32 MiB
    size_t xb_bytes = (size_t)M_DIM * K_DIM * 2;          // 128 MiB
    size_t xa_bytes = (size_t)M_DIM * 8 * 4;              // 0.5 MiB

    if (ws_size >= wb_bytes + xb_bytes + xa_bytes) {
        __hip_bfloat16* Wb = (__hip_bfloat16*)d_ws;
        __hip_bfloat16* Xb = (__hip_bfloat16*)((char*)d_ws + wb_bytes);
        float* xa = (float*)((char*)d_ws + wb_bytes + xb_bytes);

        cvt_f32_bf16<<<1024, 256, 0, stream>>>(W, Wb, (int)((size_t)N_DIM * K_DIM / 8));
        cvt_f32_bf16<<<2048, 256, 0, stream>>>(x, Xb, (int)((size_t)M_DIM * K_DIM / 8));
        compute_xa<<<M_DIM / 64, 256, 0, stream>>>(Xb, ids, lA, xa);
        gemm_bias_lora<<<(M_DIM / BM) * (N_DIM / BN), 512, 0, stream>>>(Xb, Wb, b, xa, lB, out);
    } else {
        fallback_kernel<<<dim3(N_DIM / 256, M_DIM), 256, 0, stream>>>(x, ids, W, b, lA, lB, out);
    }
}

// Round 8
// 654.158 us; speedup vs baseline: 1.1715x; 1.0275x over previous
//
#include <hip/hip_runtime.h>
#include <hip/hip_bf16.h>
#include <stdint.h>

// ConditionalLoRALinear: out = x@W^T + b + mask*(2*(x@A^T)@B^T)
// M=16384, K=4096, N=4096, R=8. bf16 MFMA path.
// R8: R7 staging/swizzle + intra-tile READ-AHEAD pipeline: each phase issues
//     the next phase's ds_reads, counted lgkmcnt waits only on the current
//     phase's -> LDS pipe drains during MFMA clusters. All of tile t resident
//     at tile entry (stage plan: P0->B-h0(t+1), P1->B-h1+A-m1(t+1),
//     P3->A-m0(t+2)); one vmcnt(2) + 2 barriers per tile.

typedef __attribute__((ext_vector_type(8))) __bf16 bf16x8;
typedef __attribute__((ext_vector_type(4))) float f32x4;

#define M_DIM 16384
#define K_DIM 4096
#define N_DIM 4096
#define BM 256
#define BN 256
#define BK 64
#define NT2 (K_DIM / BK)   // 64

// ---------------- f32 -> bf16 conversion ----------------
__global__ void cvt_f32_bf16(const float* __restrict__ in, __hip_bfloat16* __restrict__ out, int n8) {
    int i = blockIdx.x * blockDim.x + threadIdx.x;
    int stride = gridDim.x * blockDim.x;
    for (; i < n8; i += stride) {
        const float4* p = (const float4*)(in + (size_t)i * 8);
        float4 v0 = p[0], v1 = p[1];
        bf16x8 o;
        o[0] = (__bf16)v0.x; o[1] = (__bf16)v0.y; o[2] = (__bf16)v0.z; o[3] = (__bf16)v0.w;
        o[4] = (__bf16)v1.x; o[5] = (__bf16)v1.y; o[6] = (__bf16)v1.z; o[7] = (__bf16)v1.w;
        *(bf16x8*)((__hip_bfloat16*)out + (size_t)i * 8) = o;
    }
}

// ---------------- xa[m][r] = 2 * mask(m) * dot(x[m], A[r]) ----------------
__global__ void compute_xa(const __hip_bfloat16* __restrict__ Xb,
                           const int* __restrict__ ids,
                           const float* __restrict__ A,   // [8, K]
                           float* __restrict__ xa) {
    int t = threadIdx.x;
    int r = t & 63;
    int kq = t >> 6;
    int row = blockIdx.x * 64 + r;
    const __hip_bfloat16* xrow = Xb + (size_t)row * K_DIM + kq * 1024;
    float acc[8] = {0.f, 0.f, 0.f, 0.f, 0.f, 0.f, 0.f, 0.f};
    for (int i = 0; i < 128; i++) {
        bf16x8 xv = *(const bf16x8*)(xrow + i * 8);
        int kk = kq * 1024 + i * 8;
#pragma unroll
        for (int rr = 0; rr < 8; rr++) {
            const float* ap = A + rr * K_DIM + kk;
            float4 a0 = *(const float4*)ap;
            float4 a1 = *(const float4*)(ap + 4);
            acc[rr] += (float)xv[0] * a0.x + (float)xv[1] * a0.y + (float)xv[2] * a0.z + (float)xv[3] * a0.w
                     + (float)xv[4] * a1.x + (float)xv[5] * a1.y + (float)xv[6] * a1.z + (float)xv[7] * a1.w;
        }
    }
    __shared__ float red[4][64][8];
#pragma unroll
    for (int rr = 0; rr < 8; rr++) red[kq][r][rr] = acc[rr];
    __syncthreads();
    if (t < 64) {
        int rowg = blockIdx.x * 64 + t;
        float gate = (ids[rowg] == 7) ? 2.0f : 0.0f;
#pragma unroll
        for (int rr = 0; rr < 8; rr++) {
            float s = (red[0][t][rr] + red[1][t][rr]) + (red[2][t][rr] + red[3][t][rr]);
            xa[(size_t)rowg * 8 + rr] = s * gate;
        }
    }
}

// ---------------- main GEMM ----------------
__device__ __forceinline__ void gload_lds16(const void* g, void* l) {
    __builtin_amdgcn_global_load_lds(
        (const __attribute__((address_space(1))) unsigned int*)g,
        (__attribute__((address_space(3))) unsigned int*)l, 16, 0, 0);
}

#define LGKMW(n) asm volatile("s_waitcnt lgkmcnt(" #n ")" ::: "memory")
#define VMCW(n)  asm volatile("s_waitcnt vmcnt(" #n ")" ::: "memory")
#define SB0()    __builtin_amdgcn_sched_barrier(0)
#define BAR()    __builtin_amdgcn_s_barrier()
#define PRIO(p)  __builtin_amdgcn_s_setprio(p)

// LDS per buffer (64 KiB): A = 2 units of 16 KiB (unit mq: [wr0 rows mq*64..+63]
// [wr1 rows 128+mq*64..+63]); B = row-major [256][128B]. Within any row: 8
// chunks of 16 B at position p = chunk ^ (row&7) (XOR swizzle; linear dest +
// inverse-swizzled global source).
__global__ __launch_bounds__(512, 1) void gemm_bias_lora(
    const __hip_bfloat16* __restrict__ Xb,   // [M, K]
    const __hip_bfloat16* __restrict__ Wb,   // [N, K]
    const float* __restrict__ bias,          // [N]
    const float* __restrict__ xa,            // [M, 8] pre-scaled & gated
    const float* __restrict__ loraB,         // [N, 8]
    float* __restrict__ out) {
    __shared__ char smem[2 * 65536];         // 128 KiB

    int tid = threadIdx.x;
    int bid = blockIdx.x;
    int swz = (bid & 7) * 128 + (bid >> 3);  // XCD-bijective, nwg=1024
    int n_tile = swz & 15;
    int m_tile = swz >> 4;
    int m_base = m_tile * BM, n_base = n_tile * BN;
    int wave = tid >> 6, lane = tid & 63;
    int wr = wave >> 2, wc = wave & 3;       // 2M x 4N waves, per-wave 128x64
    int l15 = lane & 15, lhi = lane >> 4;
    int l8 = lane >> 3;
    int cx = ((lane & 7) ^ l8) * 16;          // staging source chunk (inverse swizzle)
    int pswz0 = ((lhi)     ^ (l15 & 7)) * 16; // read chunk byte, ks=0
    int pswz1 = ((4 + lhi) ^ (l15 & 7)) * 16; // read chunk byte, ks=1

    f32x4 acc[8][4] = {};

    const char* Abase = (const char*)(Xb + (size_t)m_base * K_DIM);
    const char* Bbase = (const char*)(Wb + (size_t)n_base * K_DIM);

    // stage unit A-mq (16 KiB, 2 gloads/thread) of K-tile kt into buffer buf
    auto stage_A = [&](int kt, int mq, int buf) {
        char* ub = smem + buf * 65536 + mq * 16384;
#pragma unroll
        for (int j = 0; j < 2; j++) {
            int rg = wave * 2 + j;                 // row-group 0..15 within unit
            int rl = rg * 8 + l8;                  // unit-local row 0..127
            int g = (rl < 64) ? (mq * 64 + rl) : (128 + mq * 64 + (rl - 64));
            gload_lds16(Abase + (size_t)g * (K_DIM * 2) + (size_t)kt * 128 + cx,
                        ub + rg * 1024 + lane * 16);
        }
    };
    // stage unit B-h (16 KiB): rows h*128 .. h*128+127, row-major
    auto stage_B = [&](int kt, int h, int buf) {
        char* ub = smem + buf * 65536 + 32768 + h * 16384;
#pragma unroll
        for (int j = 0; j < 2; j++) {
            int rg = wave * 2 + j;
            int row = h * 128 + rg * 8 + l8;
            gload_lds16(Bbase + (size_t)row * (K_DIM * 2) + (size_t)kt * 128 + cx,
                        ub + rg * 1024 + lane * 16);
        }
    };

    // prologue: tile0 all 4 units, then A-m0(1) (steady-state leftover)
    stage_A(0, 0, 0); stage_B(0, 0, 0); stage_B(0, 1, 0); stage_A(0, 1, 0);
    stage_A(1, 0, 1);
    VMCW(2);          // retire tile0's 8 loads; leave A-m0(1) in flight
    BAR();

    bf16x8 af0[4], af1[4], bf0[4], bf1[4];

    for (int t = 0; t < NT2; t++) {
        int cur = t & 1, nb = cur ^ 1;
        const char* aU0 = smem + cur * 65536 + (wr * 64 + l15) * 128;          // A unit 0
        const char* aU1 = aU0 + 16384;                                          // A unit 1
        const char* bRb = smem + cur * 65536 + 32768 + (wc * 64 + l15) * 128;  // B rows

        // ---- P0: own reads (A-m0 ks0, B ks0) + read-ahead (A-m1 ks0) ----
#pragma unroll
        for (int mi = 0; mi < 4; mi++) af0[mi] = *(const bf16x8*)(aU0 + mi * 2048 + pswz0);
#pragma unroll
        for (int ni = 0; ni < 4; ni++) bf0[ni] = *(const bf16x8*)(bRb + ni * 2048 + pswz0);
#pragma unroll
        for (int mi = 0; mi < 4; mi++) af1[mi] = *(const bf16x8*)(aU1 + mi * 2048 + pswz0);
        if (t + 1 < NT2) stage_B(t + 1, 0, nb);
        LGKMW(4); SB0();
        PRIO(1);
#pragma unroll
        for (int mi = 0; mi < 4; mi++)
#pragma unroll
            for (int ni = 0; ni < 4; ni++)
                acc[mi][ni] = __builtin_amdgcn_mfma_f32_16x16x32_bf16(af0[mi], bf0[ni], acc[mi][ni], 0, 0, 0);
        PRIO(0);

        // ---- P1: read-ahead (A-m0 ks1, B ks1); MFMA (A-m1 ks0) ----
#pragma unroll
        for (int mi = 0; mi < 4; mi++) af0[mi] = *(const bf16x8*)(aU0 + mi * 2048 + pswz1);
#pragma unroll
        for (int ni = 0; ni < 4; ni++) bf1[ni] = *(const bf16x8*)(bRb + ni * 2048 + pswz1);
        if (t + 1 < NT2) { stage_B(t + 1, 1, nb); stage_A(t + 1, 1, nb); }
        LGKMW(8); SB0();
        PRIO(1);
#pragma unroll
        for (int mi = 0; mi < 4; mi++)
#pragma unroll
            for (int ni = 0; ni < 4; ni++)
                acc[4 + mi][ni] = __builtin_amdgcn_mfma_f32_16x16x32_bf16(af1[mi], bf0[ni], acc[4 + mi][ni], 0, 0, 0);
        PRIO(0);

        // ---- P2: read-ahead (A-m1 ks1); MFMA (A-m0 ks1) ----
#pragma unroll
        for (int mi = 0; mi < 4; mi++) af1[mi] = *(const bf16x8*)(aU1 + mi * 2048 + pswz1);
        LGKMW(4); SB0();
        PRIO(1);
#pragma unroll
        for (int mi = 0; mi < 4; mi++)
#pragma unroll
            for (int ni = 0; ni < 4; ni++)
                acc[mi][ni] = __builtin_amdgcn_mfma_f32_16x16x32_bf16(af0[mi], bf1[ni], acc[mi][ni], 0, 0, 0);
        PRIO(0);
        BAR();   // all waves done reading A-m0(cur) -> region free for stage below

        // ---- P3: stage A-m0(t+2) into freed region; MFMA (A-m1 ks1) ----
        if (t + 2 < NT2) stage_A(t + 2, 0, cur);
        LGKMW(0); SB0();
        PRIO(1);
#pragma unroll
        for (int mi = 0; mi < 4; mi++)
#pragma unroll
            for (int ni = 0; ni < 4; ni++)
                acc[4 + mi][ni] = __builtin_amdgcn_mfma_f32_16x16x32_bf16(af1[mi], bf1[ni], acc[4 + mi][ni], 0, 0, 0);
        PRIO(0);
        // retire tile t+1's units {A-m0,B-h0,B-h1,A-m1}; leave A-m0(t+2)
        if (t < NT2 - 2) { VMCW(2); } else { VMCW(0); }
        BAR();
    }

    // epilogue: C/D layout col = lane&15, row = (lane>>4)*4 + reg
    int wrow = m_base + wr * 128;
    int wcol = n_base + wc * 64;
    float bv[4];
    float4 lb0[4], lb1[4];
#pragma unroll
    for (int ni = 0; ni < 4; ni++) {
        int n = wcol + ni * 16 + l15;
        bv[ni] = bias[n];
        lb0[ni] = *(const float4*)(loraB + (size_t)n * 8);
        lb1[ni] = *(const float4*)(loraB + (size_t)n * 8 + 4);
    }
#pragma unroll
    for (int mi = 0; mi < 8; mi++) {
#pragma unroll
        for (int r = 0; r < 4; r++) {
            int m = wrow + mi * 16 + lhi * 4 + r;
            float4 xa0 = *(const float4*)(xa + (size_t)m * 8);
            float4 xa1 = *(const float4*)(xa + (size_t)m * 8 + 4);
#pragma unroll
            for (int ni = 0; ni < 4; ni++) {
                int n = wcol + ni * 16 + l15;
                float lora = xa0.x * lb0[ni].x + xa0.y * lb0[ni].y + xa0.z * lb0[ni].z + xa0.w * lb0[ni].w
                           + xa1.x * lb1[ni].x + xa1.y * lb1[ni].y + xa1.z * lb1[ni].z + xa1.w * lb1[ni].w;
                out[(size_t)m * N_DIM + n] = acc[mi][ni][r] + bv[ni] + lora;
            }
        }
    }
}

// ---------------- fallback (ws too small): correct but slow ----------------
__global__ void fallback_kernel(const float* __restrict__ x, const int* __restrict__ ids,
                                const float* __restrict__ W, const float* __restrict__ b,
                                const float* __restrict__ A, const float* __restrict__ B8,
                                float* __restrict__ out) {
    __shared__ float xs[K_DIM];
    __shared__ float xa_s[8];
    int row = blockIdx.y;
    int t = threadIdx.x;
    const float* xr = x + (size_t)row * K_DIM;
    for (int k = t; k < K_DIM; k += 256) xs[k] = xr[k];
    __syncthreads();
    if (t < 8) {
        float s = 0.f;
        for (int k = 0; k < K_DIM; k++) s += xs[k] * A[t * K_DIM + k];
        xa_s[t] = (ids[row] == 7) ? s * 2.0f : 0.0f;
    }
    __syncthreads();
    int col = blockIdx.x * 256 + t;
    const float* wr = W + (size_t)col * K_DIM;
    float acc = 0.f;
    for (int k = 0; k < K_DIM; k++) acc += xs[k] * wr[k];
    float lora = 0.f;
#pragma unroll
    for (int rr = 0; rr < 8; rr++) lora += xa_s[rr] * B8[col * 8 + rr];
    out[(size_t)row * N_DIM + col] = acc + b[col] + lora;
}

extern "C" void kernel_launch(void* const* d_in, const int* in_sizes, int n_in,
                              void* d_out, int out_size, void* d_ws, size_t ws_size,
                              hipStream_t stream) {
    const float* x   = (const float*)d_in[0];
    const int*   ids = (const int*)d_in[1];
    const float* W   = (const float*)d_in[2];
    const float* b   = (const float*)d_in[3];
    const float* lA  = (const float*)d_in[4];
    const float* lB  = (const float*)d_in[5];
    float* out = (float*)d_out;

    size_t wb_bytes = (size_t)N_DIM * K_DIM * 2;          // 32 MiB
    size_t xb_bytes = (size_t)M_DIM * K_DIM * 2;          // 128 MiB
    size_t xa_bytes = (size_t)M_DIM * 8 * 4;              // 0.5 MiB

    if (ws_size >= wb_bytes + xb_bytes + xa_bytes) {
        __hip_bfloat16* Wb = (__hip_bfloat16*)d_ws;
        __hip_bfloat16* Xb = (__hip_bfloat16*)((char*)d_ws + wb_bytes);
        float* xa = (float*)((char*)d_ws + wb_bytes + xb_bytes);

        cvt_f32_bf16<<<1024, 256, 0, stream>>>(W, Wb, (int)((size_t)N_DIM * K_DIM / 8));
        cvt_f32_bf16<<<2048, 256, 0, stream>>>(x, Xb, (int)((size_t)M_DIM * K_DIM / 8));
        compute_xa<<<M_DIM / 64, 256, 0, stream>>>(Xb, ids, lA, xa);
        gemm_bias_lora<<<(M_DIM / BM) * (N_DIM / BN), 512, 0, stream>>>(Xb, Wb, b, xa, lB, out);
    } else {
        fallback_kernel<<<dim3(N_DIM / 256, M_DIM), 256, 0, stream>>>(x, ids, W, b, lA, lB, out);
    }
}

// Round 9
// 653.976 us; speedup vs baseline: 1.1719x; 1.0003x over previous
//
#include <hip/hip_runtime.h>
#include <hip/hip_bf16.h>
#include <stdint.h>

// ConditionalLoRALinear: out = x@W^T + b + mask*(2*(x@A^T)@B^T)
// M=16384, K=4096, N=4096, R=8. bf16 MFMA path.
// R9: free-running waves. A-m0 gets a 3-slot ring (3x16K) so the stage of
//     A-m0(t+2) never targets a region readable this tile -> ALL mid-tile
//     barriers removed. 1 barrier + 1 vmcnt(2) per K-tile; R8's counted-lgkm
//     read-ahead unchanged. LDS 144 KiB (A-m0 ring 48K | A-m1 2x16K | B 2x32K).

typedef __attribute__((ext_vector_type(8))) __bf16 bf16x8;
typedef __attribute__((ext_vector_type(4))) float f32x4;

#define M_DIM 16384
#define K_DIM 4096
#define N_DIM 4096
#define BM 256
#define BN 256
#define BK 64
#define NT2 (K_DIM / BK)   // 64

// ---------------- f32 -> bf16 conversion ----------------
__global__ void cvt_f32_bf16(const float* __restrict__ in, __hip_bfloat16* __restrict__ out, int n8) {
    int i = blockIdx.x * blockDim.x + threadIdx.x;
    int stride = gridDim.x * blockDim.x;
    for (; i < n8; i += stride) {
        const float4* p = (const float4*)(in + (size_t)i * 8);
        float4 v0 = p[0], v1 = p[1];
        bf16x8 o;
        o[0] = (__bf16)v0.x; o[1] = (__bf16)v0.y; o[2] = (__bf16)v0.z; o[3] = (__bf16)v0.w;
        o[4] = (__bf16)v1.x; o[5] = (__bf16)v1.y; o[6] = (__bf16)v1.z; o[7] = (__bf16)v1.w;
        *(bf16x8*)((__hip_bfloat16*)out + (size_t)i * 8) = o;
    }
}

// ---------------- xa[m][r] = 2 * mask(m) * dot(x[m], A[r]) ----------------
__global__ void compute_xa(const __hip_bfloat16* __restrict__ Xb,
                           const int* __restrict__ ids,
                           const float* __restrict__ A,   // [8, K]
                           float* __restrict__ xa) {
    int t = threadIdx.x;
    int r = t & 63;
    int kq = t >> 6;
    int row = blockIdx.x * 64 + r;
    const __hip_bfloat16* xrow = Xb + (size_t)row * K_DIM + kq * 1024;
    float acc[8] = {0.f, 0.f, 0.f, 0.f, 0.f, 0.f, 0.f, 0.f};
    for (int i = 0; i < 128; i++) {
        bf16x8 xv = *(const bf16x8*)(xrow + i * 8);
        int kk = kq * 1024 + i * 8;
#pragma unroll
        for (int rr = 0; rr < 8; rr++) {
            const float* ap = A + rr * K_DIM + kk;
            float4 a0 = *(const float4*)ap;
            float4 a1 = *(const float4*)(ap + 4);
            acc[rr] += (float)xv[0] * a0.x + (float)xv[1] * a0.y + (float)xv[2] * a0.z + (float)xv[3] * a0.w
                     + (float)xv[4] * a1.x + (float)xv[5] * a1.y + (float)xv[6] * a1.z + (float)xv[7] * a1.w;
        }
    }
    __shared__ float red[4][64][8];
#pragma unroll
    for (int rr = 0; rr < 8; rr++) red[kq][r][rr] = acc[rr];
    __syncthreads();
    if (t < 64) {
        int rowg = blockIdx.x * 64 + t;
        float gate = (ids[rowg] == 7) ? 2.0f : 0.0f;
#pragma unroll
        for (int rr = 0; rr < 8; rr++) {
            float s = (red[0][t][rr] + red[1][t][rr]) + (red[2][t][rr] + red[3][t][rr]);
            xa[(size_t)rowg * 8 + rr] = s * gate;
        }
    }
}

// ---------------- main GEMM ----------------
__device__ __forceinline__ void gload_lds16(const void* g, void* l) {
    __builtin_amdgcn_global_load_lds(
        (const __attribute__((address_space(1))) unsigned int*)g,
        (__attribute__((address_space(3))) unsigned int*)l, 16, 0, 0);
}

#define LGKMW(n) asm volatile("s_waitcnt lgkmcnt(" #n ")" ::: "memory")
#define VMCW(n)  asm volatile("s_waitcnt vmcnt(" #n ")" ::: "memory")
#define SB0()    __builtin_amdgcn_sched_barrier(0)
#define BAR()    __builtin_amdgcn_s_barrier()
#define PRIO(p)  __builtin_amdgcn_s_setprio(p)

// LDS layout (144 KiB):
//   [0, 48K):    A-m0 ring, 3 slots of 16 KiB (slot = kt % 3)
//   [48K, 80K):  A-m1, 2 buffers of 16 KiB (buf = kt & 1)
//   [80K, 144K): B, 2 buffers of 32 KiB (buf = kt & 1)
// A unit mq: unit-local rows 0-127 = [wr0: global mq*64..+63][wr1: 128+mq*64..+63].
// All units row-major [rows][128B]; within a row, 8 chunks of 16 B at position
// p = chunk ^ (row&7) (XOR swizzle; linear LDS dest + inverse-swizzled source).
__global__ __launch_bounds__(512, 1) void gemm_bias_lora(
    const __hip_bfloat16* __restrict__ Xb,   // [M, K]
    const __hip_bfloat16* __restrict__ Wb,   // [N, K]
    const float* __restrict__ bias,          // [N]
    const float* __restrict__ xa,            // [M, 8] pre-scaled & gated
    const float* __restrict__ loraB,         // [N, 8]
    float* __restrict__ out) {
    __shared__ char smem[147456];            // 144 KiB

    int tid = threadIdx.x;
    int bid = blockIdx.x;
    int swz = (bid & 7) * 128 + (bid >> 3);  // XCD-bijective, nwg=1024
    int n_tile = swz & 15;
    int m_tile = swz >> 4;
    int m_base = m_tile * BM, n_base = n_tile * BN;
    int wave = tid >> 6, lane = tid & 63;
    int wr = wave >> 2, wc = wave & 3;       // 2M x 4N waves, per-wave 128x64
    int l15 = lane & 15, lhi = lane >> 4;
    int l8 = lane >> 3;
    int cx = ((lane & 7) ^ l8) * 16;          // staging source chunk (inverse swizzle)
    int pswz0 = ((lhi)     ^ (l15 & 7)) * 16; // read chunk byte, ks=0
    int pswz1 = ((4 + lhi) ^ (l15 & 7)) * 16; // read chunk byte, ks=1

    f32x4 acc[8][4] = {};

    const char* Abase = (const char*)(Xb + (size_t)m_base * K_DIM);
    const char* Bbase = (const char*)(Wb + (size_t)n_base * K_DIM);

    // stage A unit mq of K-tile kt into LDS at 'ubase' (16 KiB, 2 gloads)
    auto stage_Au = [&](int kt, int mq, char* ubase) {
#pragma unroll
        for (int j = 0; j < 2; j++) {
            int rg = wave * 2 + j;                 // row-group 0..15 within unit
            int rl = rg * 8 + l8;                  // unit-local row 0..127
            int g = (rl < 64) ? (mq * 64 + rl) : (128 + mq * 64 + (rl - 64));
            gload_lds16(Abase + (size_t)g * (K_DIM * 2) + (size_t)kt * 128 + cx,
                        ubase + rg * 1024 + lane * 16);
        }
    };
    auto stage_B = [&](int kt, int h, int buf) {
        char* ub = smem + 81920 + buf * 32768 + h * 16384;
#pragma unroll
        for (int j = 0; j < 2; j++) {
            int rg = wave * 2 + j;
            int row = h * 128 + rg * 8 + l8;
            gload_lds16(Bbase + (size_t)row * (K_DIM * 2) + (size_t)kt * 128 + cx,
                        ub + rg * 1024 + lane * 16);
        }
    };

    // prologue: tile0 {A-m0 slot0, B buf0 h0/h1, A-m1 buf0} + A-m0(1) slot1
    stage_Au(0, 0, smem);
    stage_B(0, 0, 0); stage_B(0, 1, 0);
    stage_Au(0, 1, smem + 49152);
    stage_Au(1, 0, smem + 16384);
    VMCW(2);          // tile0's 8 retired; A-m0(1)'s 2 in flight
    BAR();

    bf16x8 af0[4], af1[4], bf0[4], bf1[4];
    int s0 = 0;       // ring slot of tile t

    for (int t = 0; t < NT2; t++) {
        int cb = t & 1, nb = cb ^ 1;
        int s2 = s0 + 2; if (s2 >= 3) s2 -= 3;   // ring slot of tile t+2
        const char* aU0 = smem + s0 * 16384 + (wr * 64 + l15) * 128;
        const char* aU1 = smem + 49152 + cb * 16384 + (wr * 64 + l15) * 128;
        const char* bRb = smem + 81920 + cb * 32768 + (wc * 64 + l15) * 128;

        // ---- P0: reads af0(ks0), bf0(ks0) + ahead af1(ks0); stage B-h0(t+1) ----
#pragma unroll
        for (int mi = 0; mi < 4; mi++) af0[mi] = *(const bf16x8*)(aU0 + mi * 2048 + pswz0);
#pragma unroll
        for (int ni = 0; ni < 4; ni++) bf0[ni] = *(const bf16x8*)(bRb + ni * 2048 + pswz0);
#pragma unroll
        for (int mi = 0; mi < 4; mi++) af1[mi] = *(const bf16x8*)(aU1 + mi * 2048 + pswz0);
        if (t + 1 < NT2) stage_B(t + 1, 0, nb);
        LGKMW(4); SB0();
        PRIO(1);
#pragma unroll
        for (int mi = 0; mi < 4; mi++)
#pragma unroll
            for (int ni = 0; ni < 4; ni++)
                acc[mi][ni] = __builtin_amdgcn_mfma_f32_16x16x32_bf16(af0[mi], bf0[ni], acc[mi][ni], 0, 0, 0);
        PRIO(0);

        // ---- P1: ahead reads af0(ks1), bf1(ks1); stage B-h1(t+1), A-m1(t+1); MFMA af1xbf0 ----
#pragma unroll
        for (int mi = 0; mi < 4; mi++) af0[mi] = *(const bf16x8*)(aU0 + mi * 2048 + pswz1);
#pragma unroll
        for (int ni = 0; ni < 4; ni++) bf1[ni] = *(const bf16x8*)(bRb + ni * 2048 + pswz1);
        if (t + 1 < NT2) { stage_B(t + 1, 1, nb); stage_Au(t + 1, 1, smem + 49152 + nb * 16384); }
        LGKMW(8); SB0();
        PRIO(1);
#pragma unroll
        for (int mi = 0; mi < 4; mi++)
#pragma unroll
            for (int ni = 0; ni < 4; ni++)
                acc[4 + mi][ni] = __builtin_amdgcn_mfma_f32_16x16x32_bf16(af1[mi], bf0[ni], acc[4 + mi][ni], 0, 0, 0);
        PRIO(0);

        // ---- P2: ahead read af1(ks1); MFMA af0xbf1 ----
#pragma unroll
        for (int mi = 0; mi < 4; mi++) af1[mi] = *(const bf16x8*)(aU1 + mi * 2048 + pswz1);
        LGKMW(4); SB0();
        PRIO(1);
#pragma unroll
        for (int mi = 0; mi < 4; mi++)
#pragma unroll
            for (int ni = 0; ni < 4; ni++)
                acc[mi][ni] = __builtin_amdgcn_mfma_f32_16x16x32_bf16(af0[mi], bf1[ni], acc[mi][ni], 0, 0, 0);
        PRIO(0);

        // ---- P3: stage A-m0(t+2) -> ring slot s2 (not readable this tile); MFMA af1xbf1 ----
        if (t + 2 < NT2) stage_Au(t + 2, 0, smem + s2 * 16384);
        LGKMW(0); SB0();
        PRIO(1);
#pragma unroll
        for (int mi = 0; mi < 4; mi++)
#pragma unroll
            for (int ni = 0; ni < 4; ni++)
                acc[4 + mi][ni] = __builtin_amdgcn_mfma_f32_16x16x32_bf16(af1[mi], bf1[ni], acc[4 + mi][ni], 0, 0, 0);
        PRIO(0);
        // retire tile t+1's units {A-m0, B-h0, B-h1, A-m1}; leave A-m0(t+2)
        if (t < NT2 - 2) { VMCW(2); } else { VMCW(0); }
        BAR();

        s0 = s0 + 1; if (s0 >= 3) s0 -= 3;
    }

    // epilogue: C/D layout col = lane&15, row = (lane>>4)*4 + reg
    int wrow = m_base + wr * 128;
    int wcol = n_base + wc * 64;
    float bv[4];
    float4 lb0[4], lb1[4];
#pragma unroll
    for (int ni = 0; ni < 4; ni++) {
        int n = wcol + ni * 16 + l15;
        bv[ni] = bias[n];
        lb0[ni] = *(const float4*)(loraB + (size_t)n * 8);
        lb1[ni] = *(const float4*)(loraB + (size_t)n * 8 + 4);
    }
#pragma unroll
    for (int mi = 0; mi < 8; mi++) {
#pragma unroll
        for (int r = 0; r < 4; r++) {
            int m = wrow + mi * 16 + lhi * 4 + r;
            float4 xa0 = *(const float4*)(xa + (size_t)m * 8);
            float4 xa1 = *(const float4*)(xa + (size_t)m * 8 + 4);
#pragma unroll
            for (int ni = 0; ni < 4; ni++) {
                int n = wcol + ni * 16 + l15;
                float lora = xa0.x * lb0[ni].x + xa0.y * lb0[ni].y + xa0.z * lb0[ni].z + xa0.w * lb0[ni].w
                           + xa1.x * lb1[ni].x + xa1.y * lb1[ni].y + xa1.z * lb1[ni].z + xa1.w * lb1[ni].w;
                out[(size_t)m * N_DIM + n] = acc[mi][ni][r] + bv[ni] + lora;
            }
        }
    }
}

// ---------------- fallback (ws too small): correct but slow ----------------
__global__ void fallback_kernel(const float* __restrict__ x, const int* __restrict__ ids,
                                const float* __restrict__ W, const float* __restrict__ b,
                                const float* __restrict__ A, const float* __restrict__ B8,
                                float* __restrict__ out) {
    __shared__ float xs[K_DIM];
    __shared__ float xa_s[8];
    int row = blockIdx.y;
    int t = threadIdx.x;
    const float* xr = x + (size_t)row * K_DIM;
    for (int k = t; k < K_DIM; k += 256) xs[k] = xr[k];
    __syncthreads();
    if (t < 8) {
        float s = 0.f;
        for (int k = 0; k < K_DIM; k++) s += xs[k] * A[t * K_DIM + k];
        xa_s[t] = (ids[row] == 7) ? s * 2.0f : 0.0f;
    }
    __syncthreads();
    int col = blockIdx.x * 256 + t;
    const float* wr = W + (size_t)col * K_DIM;
    float acc = 0.f;
    for (int k = 0; k < K_DIM; k++) acc += xs[k] * wr[k];
    float lora = 0.f;
#pragma unroll
    for (int rr = 0; rr < 8; rr++) lora += xa_s[rr] * B8[col * 8 + rr];
    out[(size_t)row * N_DIM + col] = acc + b[col] + lora;
}

extern "C" void kernel_launch(void* const* d_in, const int* in_sizes, int n_in,
                              void* d_out, int out_size, void* d_ws, size_t ws_size,
                              hipStream_t stream) {
    const float* x   = (const float*)d_in[0];
    const int*   ids = (const int*)d_in[1];
    const float* W   = (const float*)d_in[2];
    const float* b   = (const float*)d_in[3];
    const float* lA  = (const float*)d_in[4];
    const float* lB  = (const float*)d_in[5];
    float* out = (float*)d_out;

    size_t wb_bytes = (size_t)N_DIM * K_DIM * 2;          // 32 MiB
    size_t xb_bytes = (size_t)M_DIM * K_DIM * 2;          // 128 MiB
    size_t xa_bytes = (size_t)M_DIM * 8 * 4;              // 0.5 MiB

    if (ws_size >= wb_bytes + xb_bytes + xa_bytes) {
        __hip_bfloat16* Wb = (__hip_bfloat16*)d_ws;
        __hip_bfloat16* Xb = (__hip_bfloat16*)((char*)d_ws + wb_bytes);
        float* xa = (float*)((char*)d_ws + wb_bytes + xb_bytes);

        cvt_f32_bf16<<<1024, 256, 0, stream>>>(W, Wb, (int)((size_t)N_DIM * K_DIM / 8));
        cvt_f32_bf16<<<2048, 256, 0, stream>>>(x, Xb, (int)((size_t)M_DIM * K_DIM / 8));
        compute_xa<<<M_DIM / 64, 256, 0, stream>>>(Xb, ids, lA, xa);
        gemm_bias_lora<<<(M_DIM / BM) * (N_DIM / BN), 512, 0, stream>>>(Xb, Wb, b, xa, lB, out);
    } else {
        fallback_kernel<<<dim3(N_DIM / 256, M_DIM), 256, 0, stream>>>(x, ids, W, b, lA, lB, out);
    }
}

// Round 10
// 582.072 us; speedup vs baseline: 1.3166x; 1.1235x over previous
//
#include <hip/hip_runtime.h>
#include <hip/hip_bf16.h>
#include <stdint.h>

// ConditionalLoRALinear: out = x@W^T + b + mask*(2*(x@A^T)@B^T)
// M=16384, K=4096, N=4096, R=8. bf16 MFMA path.
// R10: (a) SIMD-pair phase skew: wr=1 waves (second wave on each SIMD) process
//      quadrants ks1-first (pswz0<->pswz1 swap) so the wave-pair's ds_read
//      bursts and MFMA clusters interleave instead of convoying. All of tile t
//      is resident at tile entry (R8 ledger), so order is free.
//      (b) fused prep: cvt_x_xa converts x->bf16 AND computes xa in one pass
//      (A staged in LDS as bf16); xa kernel eliminated.

typedef __attribute__((ext_vector_type(8))) __bf16 bf16x8;
typedef __attribute__((ext_vector_type(4))) float f32x4;

#define M_DIM 16384
#define K_DIM 4096
#define N_DIM 4096
#define BM 256
#define BN 256
#define BK 64
#define NT2 (K_DIM / BK)   // 64

// ---------------- f32 -> bf16 conversion ----------------
__global__ void cvt_f32_bf16(const float* __restrict__ in, __hip_bfloat16* __restrict__ out, int n8) {
    int i = blockIdx.x * blockDim.x + threadIdx.x;
    int stride = gridDim.x * blockDim.x;
    for (; i < n8; i += stride) {
        const float4* p = (const float4*)(in + (size_t)i * 8);
        float4 v0 = p[0], v1 = p[1];
        bf16x8 o;
        o[0] = (__bf16)v0.x; o[1] = (__bf16)v0.y; o[2] = (__bf16)v0.z; o[3] = (__bf16)v0.w;
        o[4] = (__bf16)v1.x; o[5] = (__bf16)v1.y; o[6] = (__bf16)v1.z; o[7] = (__bf16)v1.w;
        *(bf16x8*)((__hip_bfloat16*)out + (size_t)i * 8) = o;
    }
}

// ---------------- fused: x -> Xb (bf16) AND xa[m][r] = 2*mask*dot(x[m],A[r]) ----------------
// 4096 blocks x 256 threads; wave w handles row blockIdx*4+w (one wave per row).
// A (bf16, 64 KiB) staged in LDS once per block; per-lane 8x FMA groups; wave
// shuffle-reduce; lane 0 gates by ids and writes xa.
__global__ __launch_bounds__(256) void cvt_x_xa(
    const float* __restrict__ x, const int* __restrict__ ids,
    const __hip_bfloat16* __restrict__ Abf,   // [8,4096] bf16
    __hip_bfloat16* __restrict__ Xb, float* __restrict__ xa) {
    __shared__ __hip_bfloat16 As[8 * 4096];   // 64 KiB
    int tid = threadIdx.x;
    for (int i = tid; i < 8 * 4096 / 8; i += 256)
        *(bf16x8*)(As + i * 8) = *(const bf16x8*)(Abf + i * 8);
    __syncthreads();

    int wave = tid >> 6, lane = tid & 63;
    int row = blockIdx.x * 4 + wave;
    const float* xr = x + (size_t)row * K_DIM;
    __hip_bfloat16* xo = Xb + (size_t)row * K_DIM;
    float s[8] = {0.f, 0.f, 0.f, 0.f, 0.f, 0.f, 0.f, 0.f};
#pragma unroll
    for (int j = 0; j < 8; j++) {
        int k = j * 512 + lane * 8;
        float4 v0 = *(const float4*)(xr + k);
        float4 v1 = *(const float4*)(xr + k + 4);
        bf16x8 o;
        o[0] = (__bf16)v0.x; o[1] = (__bf16)v0.y; o[2] = (__bf16)v0.z; o[3] = (__bf16)v0.w;
        o[4] = (__bf16)v1.x; o[5] = (__bf16)v1.y; o[6] = (__bf16)v1.z; o[7] = (__bf16)v1.w;
        *(bf16x8*)(xo + k) = o;
#pragma unroll
        for (int r = 0; r < 8; r++) {
            bf16x8 av = *(const bf16x8*)(As + r * 4096 + k);   // lane-linear, conflict-free
            s[r] += v0.x * (float)av[0] + v0.y * (float)av[1] + v0.z * (float)av[2] + v0.w * (float)av[3]
                  + v1.x * (float)av[4] + v1.y * (float)av[5] + v1.z * (float)av[6] + v1.w * (float)av[7];
        }
    }
#pragma unroll
    for (int r = 0; r < 8; r++) {
        float v = s[r];
        for (int off = 32; off; off >>= 1) v += __shfl_down(v, off);
        s[r] = v;
    }
    if (lane == 0) {
        float gate = (ids[row] == 7) ? 2.0f : 0.0f;
#pragma unroll
        for (int r = 0; r < 8; r++) xa[(size_t)row * 8 + r] = s[r] * gate;
    }
}

// ---------------- main GEMM ----------------
__device__ __forceinline__ void gload_lds16(const void* g, void* l) {
    __builtin_amdgcn_global_load_lds(
        (const __attribute__((address_space(1))) unsigned int*)g,
        (__attribute__((address_space(3))) unsigned int*)l, 16, 0, 0);
}

#define LGKMW(n) asm volatile("s_waitcnt lgkmcnt(" #n ")" ::: "memory")
#define VMCW(n)  asm volatile("s_waitcnt vmcnt(" #n ")" ::: "memory")
#define SB0()    __builtin_amdgcn_sched_barrier(0)
#define BAR()    __builtin_amdgcn_s_barrier()
#define PRIO(p)  __builtin_amdgcn_s_setprio(p)

// LDS layout (144 KiB):
//   [0, 48K):    A-m0 ring, 3 slots of 16 KiB (slot = kt % 3)
//   [48K, 80K):  A-m1, 2 buffers of 16 KiB (buf = kt & 1)
//   [80K, 144K): B, 2 buffers of 32 KiB (buf = kt & 1)
// Unit mq rows: [wr0: global mq*64..+63][wr1: 128+mq*64..+63]. Rows 128 B;
// 8 chunks of 16 B at position p = chunk ^ (row&7) (XOR swizzle; linear dest +
// inverse-swizzled global source). All of tile t is resident at the tile-entry
// barrier (retire ledger: VMCW(2) at end of t-1 retires everything except
// A-m0(t+1)) -> quadrant order within a tile is free per wave.
__global__ __launch_bounds__(512, 1) void gemm_bias_lora(
    const __hip_bfloat16* __restrict__ Xb,   // [M, K]
    const __hip_bfloat16* __restrict__ Wb,   // [N, K]
    const float* __restrict__ bias,          // [N]
    const float* __restrict__ xa,            // [M, 8] pre-scaled & gated
    const float* __restrict__ loraB,         // [N, 8]
    float* __restrict__ out) {
    __shared__ char smem[147456];            // 144 KiB

    int tid = threadIdx.x;
    int bid = blockIdx.x;
    int swz = (bid & 7) * 128 + (bid >> 3);  // XCD-bijective, nwg=1024
    int n_tile = swz & 15;
    int m_tile = swz >> 4;
    int m_base = m_tile * BM, n_base = n_tile * BN;
    int wave = tid >> 6, lane = tid & 63;
    int wr = wave >> 2, wc = wave & 3;       // 2M x 4N waves, per-wave 128x64
    int l15 = lane & 15, lhi = lane >> 4;
    int l8 = lane >> 3;
    int cx = ((lane & 7) ^ l8) * 16;          // staging source chunk (inverse swizzle)
    int pswz0 = ((lhi)     ^ (l15 & 7)) * 16; // read chunk byte, ks=0
    int pswz1 = ((4 + lhi) ^ (l15 & 7)) * 16; // read chunk byte, ks=1
    // SIMD-pair skew: wr=1 waves (second wave of each SIMD) do ks1-half first.
    int psA = wr ? pswz1 : pswz0;
    int psB = wr ? pswz0 : pswz1;

    f32x4 acc[8][4] = {};

    const char* Abase = (const char*)(Xb + (size_t)m_base * K_DIM);
    const char* Bbase = (const char*)(Wb + (size_t)n_base * K_DIM);

    auto stage_Au = [&](int kt, int mq, char* ubase) {
#pragma unroll
        for (int j = 0; j < 2; j++) {
            int rg = wave * 2 + j;                 // row-group 0..15 within unit
            int rl = rg * 8 + l8;                  // unit-local row 0..127
            int g = (rl < 64) ? (mq * 64 + rl) : (128 + mq * 64 + (rl - 64));
            gload_lds16(Abase + (size_t)g * (K_DIM * 2) + (size_t)kt * 128 + cx,
                        ubase + rg * 1024 + lane * 16);
        }
    };
    auto stage_B = [&](int kt, int h, int buf) {
        char* ub = smem + 81920 + buf * 32768 + h * 16384;
#pragma unroll
        for (int j = 0; j < 2; j++) {
            int rg = wave * 2 + j;
            int row = h * 128 + rg * 8 + l8;
            gload_lds16(Bbase + (size_t)row * (K_DIM * 2) + (size_t)kt * 128 + cx,
                        ub + rg * 1024 + lane * 16);
        }
    };

    // prologue: tile0 {A-m0 slot0, B buf0 h0/h1, A-m1 buf0} + A-m0(1) slot1
    stage_Au(0, 0, smem);
    stage_B(0, 0, 0); stage_B(0, 1, 0);
    stage_Au(0, 1, smem + 49152);
    stage_Au(1, 0, smem + 16384);
    VMCW(2);
    BAR();

    bf16x8 af0[4], af1[4], bf0[4], bf1[4];
    int s0 = 0;

    for (int t = 0; t < NT2; t++) {
        int cb = t & 1, nb = cb ^ 1;
        int s2 = s0 + 2; if (s2 >= 3) s2 -= 3;
        const char* aU0 = smem + s0 * 16384 + (wr * 64 + l15) * 128;
        const char* aU1 = smem + 49152 + cb * 16384 + (wr * 64 + l15) * 128;
        const char* bRb = smem + 81920 + cb * 32768 + (wc * 64 + l15) * 128;

        // ---- P0: reads af0(ksA), bf0(ksA) + ahead af1(ksA); stage B-h0(t+1) ----
#pragma unroll
        for (int mi = 0; mi < 4; mi++) af0[mi] = *(const bf16x8*)(aU0 + mi * 2048 + psA);
#pragma unroll
        for (int ni = 0; ni < 4; ni++) bf0[ni] = *(const bf16x8*)(bRb + ni * 2048 + psA);
#pragma unroll
        for (int mi = 0; mi < 4; mi++) af1[mi] = *(const bf16x8*)(aU1 + mi * 2048 + psA);
        if (t + 1 < NT2) stage_B(t + 1, 0, nb);
        LGKMW(4); SB0();
        PRIO(1);
#pragma unroll
        for (int mi = 0; mi < 4; mi++)
#pragma unroll
            for (int ni = 0; ni < 4; ni++)
                acc[mi][ni] = __builtin_amdgcn_mfma_f32_16x16x32_bf16(af0[mi], bf0[ni], acc[mi][ni], 0, 0, 0);
        PRIO(0);

        // ---- P1: ahead reads af0(ksB), bf1(ksB); stage B-h1(t+1), A-m1(t+1); MFMA af1xbf0 ----
#pragma unroll
        for (int mi = 0; mi < 4; mi++) af0[mi] = *(const bf16x8*)(aU0 + mi * 2048 + psB);
#pragma unroll
        for (int ni = 0; ni < 4; ni++) bf1[ni] = *(const bf16x8*)(bRb + ni * 2048 + psB);
        if (t + 1 < NT2) { stage_B(t + 1, 1, nb); stage_Au(t + 1, 1, smem + 49152 + nb * 16384); }
        LGKMW(8); SB0();
        PRIO(1);
#pragma unroll
        for (int mi = 0; mi < 4; mi++)
#pragma unroll
            for (int ni = 0; ni < 4; ni++)
                acc[4 + mi][ni] = __builtin_amdgcn_mfma_f32_16x16x32_bf16(af1[mi], bf0[ni], acc[4 + mi][ni], 0, 0, 0);
        PRIO(0);

        // ---- P2: ahead read af1(ksB); MFMA af0xbf1 ----
#pragma unroll
        for (int mi = 0; mi < 4; mi++) af1[mi] = *(const bf16x8*)(aU1 + mi * 2048 + psB);
        LGKMW(4); SB0();
        PRIO(1);
#pragma unroll
        for (int mi = 0; mi < 4; mi++)
#pragma unroll
            for (int ni = 0; ni < 4; ni++)
                acc[mi][ni] = __builtin_amdgcn_mfma_f32_16x16x32_bf16(af0[mi], bf1[ni], acc[mi][ni], 0, 0, 0);
        PRIO(0);

        // ---- P3: stage A-m0(t+2) -> ring slot s2; MFMA af1xbf1 ----
        if (t + 2 < NT2) stage_Au(t + 2, 0, smem + s2 * 16384);
        LGKMW(0); SB0();
        PRIO(1);
#pragma unroll
        for (int mi = 0; mi < 4; mi++)
#pragma unroll
            for (int ni = 0; ni < 4; ni++)
                acc[4 + mi][ni] = __builtin_amdgcn_mfma_f32_16x16x32_bf16(af1[mi], bf1[ni], acc[4 + mi][ni], 0, 0, 0);
        PRIO(0);
        if (t < NT2 - 2) { VMCW(2); } else { VMCW(0); }
        BAR();

        s0 = s0 + 1; if (s0 >= 3) s0 -= 3;
    }

    // epilogue: C/D layout col = lane&15, row = (lane>>4)*4 + reg
    int wrow = m_base + wr * 128;
    int wcol = n_base + wc * 64;
    float bv[4];
    float4 lb0[4], lb1[4];
#pragma unroll
    for (int ni = 0; ni < 4; ni++) {
        int n = wcol + ni * 16 + l15;
        bv[ni] = bias[n];
        lb0[ni] = *(const float4*)(loraB + (size_t)n * 8);
        lb1[ni] = *(const float4*)(loraB + (size_t)n * 8 + 4);
    }
#pragma unroll
    for (int mi = 0; mi < 8; mi++) {
#pragma unroll
        for (int r = 0; r < 4; r++) {
            int m = wrow + mi * 16 + lhi * 4 + r;
            float4 xa0 = *(const float4*)(xa + (size_t)m * 8);
            float4 xa1 = *(const float4*)(xa + (size_t)m * 8 + 4);
#pragma unroll
            for (int ni = 0; ni < 4; ni++) {
                int n = wcol + ni * 16 + l15;
                float lora = xa0.x * lb0[ni].x + xa0.y * lb0[ni].y + xa0.z * lb0[ni].z + xa0.w * lb0[ni].w
                           + xa1.x * lb1[ni].x + xa1.y * lb1[ni].y + xa1.z * lb1[ni].z + xa1.w * lb1[ni].w;
                out[(size_t)m * N_DIM + n] = acc[mi][ni][r] + bv[ni] + lora;
            }
        }
    }
}

// ---------------- fallback (ws too small): correct but slow ----------------
__global__ void fallback_kernel(const float* __restrict__ x, const int* __restrict__ ids,
                                const float* __restrict__ W, const float* __restrict__ b,
                                const float* __restrict__ A, const float* __restrict__ B8,
                                float* __restrict__ out) {
    __shared__ float xs[K_DIM];
    __shared__ float xa_s[8];
    int row = blockIdx.y;
    int t = threadIdx.x;
    const float* xr = x + (size_t)row * K_DIM;
    for (int k = t; k < K_DIM; k += 256) xs[k] = xr[k];
    __syncthreads();
    if (t < 8) {
        float s = 0.f;
        for (int k = 0; k < K_DIM; k++) s += xs[k] * A[t * K_DIM + k];
        xa_s[t] = (ids[row] == 7) ? s * 2.0f : 0.0f;
    }
    __syncthreads();
    int col = blockIdx.x * 256 + t;
    const float* wr = W + (size_t)col * K_DIM;
    float acc = 0.f;
    for (int k = 0; k < K_DIM; k++) acc += xs[k] * wr[k];
    float lora = 0.f;
#pragma unroll
    for (int rr = 0; rr < 8; rr++) lora += xa_s[rr] * B8[col * 8 + rr];
    out[(size_t)row * N_DIM + col] = acc + b[col] + lora;
}

extern "C" void kernel_launch(void* const* d_in, const int* in_sizes, int n_in,
                              void* d_out, int out_size, void* d_ws, size_t ws_size,
                              hipStream_t stream) {
    const float* x   = (const float*)d_in[0];
    const int*   ids = (const int*)d_in[1];
    const float* W   = (const float*)d_in[2];
    const float* b   = (const float*)d_in[3];
    const float* lA  = (const float*)d_in[4];
    const float* lB  = (const float*)d_in[5];
    float* out = (float*)d_out;

    size_t wb_bytes = (size_t)N_DIM * K_DIM * 2;          // 32 MiB
    size_t xb_bytes = (size_t)M_DIM * K_DIM * 2;          // 128 MiB
    size_t xa_bytes = (size_t)M_DIM * 8 * 4;              // 0.5 MiB
    size_t ab_bytes = (size_t)8 * K_DIM * 2;              // 64 KiB

    if (ws_size >= wb_bytes + xb_bytes + xa_bytes + ab_bytes) {
        __hip_bfloat16* Wb  = (__hip_bfloat16*)d_ws;
        __hip_bfloat16* Xb  = (__hip_bfloat16*)((char*)d_ws + wb_bytes);
        float*          xav = (float*)((char*)d_ws + wb_bytes + xb_bytes);
        __hip_bfloat16* Abf = (__hip_bfloat16*)((char*)d_ws + wb_bytes + xb_bytes + xa_bytes);

        cvt_f32_bf16<<<1024, 256, 0, stream>>>(W, Wb, (int)((size_t)N_DIM * K_DIM / 8));
        cvt_f32_bf16<<<16, 256, 0, stream>>>(lA, Abf, (int)(8 * K_DIM / 8));
        cvt_x_xa<<<M_DIM / 4, 256, 0, stream>>>(x, ids, Abf, Xb, xav);
        gemm_bias_lora<<<(M_DIM / BM) * (N_DIM / BN), 512, 0, stream>>>(Xb, Wb, b, xav, lB, out);
    } else {
        fallback_kernel<<<dim3(N_DIM / 256, M_DIM), 256, 0, stream>>>(x, ids, W, b, lA, lB, out);
    }
}

// Round 12
// 572.268 us; speedup vs baseline: 1.3392x; 1.0171x over previous
//
#include <hip/hip_runtime.h>
#include <hip/hip_bf16.h>
#include <stdint.h>

// ConditionalLoRALinear: out = x@W^T + b + mask*(2*(x@A^T)@B^T)
// M=16384, K=4096, N=4096, R=8. bf16 MFMA path.
// R12: GEMM reverted to the VERIFIED R10 kernel (466us, MfmaUtil 56.6, 0
//      conflicts). Prep streamlined: W+A conversion merged into one launch;
//      cvt_x_xa at 2048 blocks x 8 rows (halves per-block A-staging traffic).

typedef __attribute__((ext_vector_type(8))) __bf16 bf16x8;
typedef __attribute__((ext_vector_type(4))) float f32x4;

#define M_DIM 16384
#define K_DIM 4096
#define N_DIM 4096
#define BM 256
#define BN 256
#define BK 64
#define NT2 (K_DIM / BK)   // 64

// ---------------- merged W + lora_A f32 -> bf16 conversion ----------------
__global__ __launch_bounds__(256) void cvt_wa(
    const float* __restrict__ W, __hip_bfloat16* __restrict__ Wb,
    const float* __restrict__ A, __hip_bfloat16* __restrict__ Ab) {
    int b = blockIdx.x;
    if (b < 1024) {
        int i = b * 256 + threadIdx.x;
        const int n8 = N_DIM * K_DIM / 8;
        const int stride = 1024 * 256;
        for (; i < n8; i += stride) {
            const float4* p = (const float4*)(W + (size_t)i * 8);
            float4 v0 = p[0], v1 = p[1];
            bf16x8 o;
            o[0] = (__bf16)v0.x; o[1] = (__bf16)v0.y; o[2] = (__bf16)v0.z; o[3] = (__bf16)v0.w;
            o[4] = (__bf16)v1.x; o[5] = (__bf16)v1.y; o[6] = (__bf16)v1.z; o[7] = (__bf16)v1.w;
            *(bf16x8*)((__hip_bfloat16*)Wb + (size_t)i * 8) = o;
        }
    } else {
        int i = (b - 1024) * 256 + threadIdx.x;
        if (i < 8 * K_DIM / 8) {
            const float4* p = (const float4*)(A + (size_t)i * 8);
            float4 v0 = p[0], v1 = p[1];
            bf16x8 o;
            o[0] = (__bf16)v0.x; o[1] = (__bf16)v0.y; o[2] = (__bf16)v0.z; o[3] = (__bf16)v0.w;
            o[4] = (__bf16)v1.x; o[5] = (__bf16)v1.y; o[6] = (__bf16)v1.z; o[7] = (__bf16)v1.w;
            *(bf16x8*)((__hip_bfloat16*)Ab + (size_t)i * 8) = o;
        }
    }
}

// ---------------- fused: x -> Xb (bf16) AND xa[m][r] = 2*mask*dot(x[m],A[r]) ----------------
// 2048 blocks x 256 threads; wave w handles rows blockIdx*8 + w*2 + {0,1}.
// A (bf16, 64 KiB) staged in LDS once per block (2 blocks/CU resident).
__global__ __launch_bounds__(256) void cvt_x_xa(
    const float* __restrict__ x, const int* __restrict__ ids,
    const __hip_bfloat16* __restrict__ Abf,   // [8,4096] bf16
    __hip_bfloat16* __restrict__ Xb, float* __restrict__ xa) {
    __shared__ __hip_bfloat16 As[8 * 4096];   // 64 KiB
    int tid = threadIdx.x;
    for (int i = tid; i < 8 * 4096 / 8; i += 256)
        *(bf16x8*)(As + i * 8) = *(const bf16x8*)(Abf + i * 8);
    __syncthreads();

    int wave = tid >> 6, lane = tid & 63;
#pragma unroll
    for (int rr = 0; rr < 2; rr++) {
        int row = blockIdx.x * 8 + wave * 2 + rr;
        const float* xr = x + (size_t)row * K_DIM;
        __hip_bfloat16* xo = Xb + (size_t)row * K_DIM;
        float s[8] = {0.f, 0.f, 0.f, 0.f, 0.f, 0.f, 0.f, 0.f};
#pragma unroll
        for (int j = 0; j < 8; j++) {
            int k = j * 512 + lane * 8;
            float4 v0 = *(const float4*)(xr + k);
            float4 v1 = *(const float4*)(xr + k + 4);
            bf16x8 o;
            o[0] = (__bf16)v0.x; o[1] = (__bf16)v0.y; o[2] = (__bf16)v0.z; o[3] = (__bf16)v0.w;
            o[4] = (__bf16)v1.x; o[5] = (__bf16)v1.y; o[6] = (__bf16)v1.z; o[7] = (__bf16)v1.w;
            *(bf16x8*)(xo + k) = o;
#pragma unroll
            for (int r = 0; r < 8; r++) {
                bf16x8 av = *(const bf16x8*)(As + r * 4096 + k);
                s[r] += v0.x * (float)av[0] + v0.y * (float)av[1] + v0.z * (float)av[2] + v0.w * (float)av[3]
                      + v1.x * (float)av[4] + v1.y * (float)av[5] + v1.z * (float)av[6] + v1.w * (float)av[7];
            }
        }
#pragma unroll
        for (int r = 0; r < 8; r++) {
            float v = s[r];
            for (int off = 32; off; off >>= 1) v += __shfl_down(v, off);
            s[r] = v;
        }
        if (lane == 0) {
            float gate = (ids[row] == 7) ? 2.0f : 0.0f;
#pragma unroll
            for (int r = 0; r < 8; r++) xa[(size_t)row * 8 + r] = s[r] * gate;
        }
    }
}

// ---------------- main GEMM (VERIFIED R10 kernel, byte-identical) ----------------
__device__ __forceinline__ void gload_lds16(const void* g, void* l) {
    __builtin_amdgcn_global_load_lds(
        (const __attribute__((address_space(1))) unsigned int*)g,
        (__attribute__((address_space(3))) unsigned int*)l, 16, 0, 0);
}

#define LGKMW(n) asm volatile("s_waitcnt lgkmcnt(" #n ")" ::: "memory")
#define VMCW(n)  asm volatile("s_waitcnt vmcnt(" #n ")" ::: "memory")
#define SB0()    __builtin_amdgcn_sched_barrier(0)
#define BAR()    __builtin_amdgcn_s_barrier()
#define PRIO(p)  __builtin_amdgcn_s_setprio(p)

// LDS layout (144 KiB):
//   [0, 48K):    A-m0 ring, 3 slots of 16 KiB (slot = kt % 3)
//   [48K, 80K):  A-m1, 2 buffers of 16 KiB (buf = kt & 1)
//   [80K, 144K): B, 2 buffers of 32 KiB (buf = kt & 1)
// Unit mq rows: [wr0: global mq*64..+63][wr1: 128+mq*64..+63]. Rows 128 B;
// 8 chunks of 16 B at position p = chunk ^ (row&7) (XOR swizzle; linear dest +
// inverse-swizzled global source). All of tile t resident at tile-entry barrier.
__global__ __launch_bounds__(512, 1) void gemm_bias_lora(
    const __hip_bfloat16* __restrict__ Xb,   // [M, K]
    const __hip_bfloat16* __restrict__ Wb,   // [N, K]
    const float* __restrict__ bias,          // [N]
    const float* __restrict__ xa,            // [M, 8] pre-scaled & gated
    const float* __restrict__ loraB,         // [N, 8]
    float* __restrict__ out) {
    __shared__ char smem[147456];            // 144 KiB

    int tid = threadIdx.x;
    int bid = blockIdx.x;
    int swz = (bid & 7) * 128 + (bid >> 3);  // XCD-bijective, nwg=1024
    int n_tile = swz & 15;
    int m_tile = swz >> 4;
    int m_base = m_tile * BM, n_base = n_tile * BN;
    int wave = tid >> 6, lane = tid & 63;
    int wr = wave >> 2, wc = wave & 3;       // 2M x 4N waves, per-wave 128x64
    int l15 = lane & 15, lhi = lane >> 4;
    int l8 = lane >> 3;
    int cx = ((lane & 7) ^ l8) * 16;          // staging source chunk (inverse swizzle)
    int pswz0 = ((lhi)     ^ (l15 & 7)) * 16; // read chunk byte, ks=0
    int pswz1 = ((4 + lhi) ^ (l15 & 7)) * 16; // read chunk byte, ks=1
    int psA = wr ? pswz1 : pswz0;             // SIMD-pair skew (verified neutral)
    int psB = wr ? pswz0 : pswz1;

    f32x4 acc[8][4] = {};

    const char* Abase = (const char*)(Xb + (size_t)m_base * K_DIM);
    const char* Bbase = (const char*)(Wb + (size_t)n_base * K_DIM);

    auto stage_Au = [&](int kt, int mq, char* ubase) {
#pragma unroll
        for (int j = 0; j < 2; j++) {
            int rg = wave * 2 + j;
            int rl = rg * 8 + l8;
            int g = (rl < 64) ? (mq * 64 + rl) : (128 + mq * 64 + (rl - 64));
            gload_lds16(Abase + (size_t)g * (K_DIM * 2) + (size_t)kt * 128 + cx,
                        ubase + rg * 1024 + lane * 16);
        }
    };
    auto stage_B = [&](int kt, int h, int buf) {
        char* ub = smem + 81920 + buf * 32768 + h * 16384;
#pragma unroll
        for (int j = 0; j < 2; j++) {
            int rg = wave * 2 + j;
            int row = h * 128 + rg * 8 + l8;
            gload_lds16(Bbase + (size_t)row * (K_DIM * 2) + (size_t)kt * 128 + cx,
                        ub + rg * 1024 + lane * 16);
        }
    };

    // prologue: tile0 {A-m0 slot0, B buf0 h0/h1, A-m1 buf0} + A-m0(1) slot1
    stage_Au(0, 0, smem);
    stage_B(0, 0, 0); stage_B(0, 1, 0);
    stage_Au(0, 1, smem + 49152);
    stage_Au(1, 0, smem + 16384);
    VMCW(2);
    BAR();

    bf16x8 af0[4], af1[4], bf0[4], bf1[4];
    int s0 = 0;

    for (int t = 0; t < NT2; t++) {
        int cb = t & 1, nb = cb ^ 1;
        int s2 = s0 + 2; if (s2 >= 3) s2 -= 3;
        const char* aU0 = smem + s0 * 16384 + (wr * 64 + l15) * 128;
        const char* aU1 = smem + 49152 + cb * 16384 + (wr * 64 + l15) * 128;
        const char* bRb = smem + 81920 + cb * 32768 + (wc * 64 + l15) * 128;

        // ---- P0: reads af0(ksA), bf0(ksA) + ahead af1(ksA); stage B-h0(t+1) ----
#pragma unroll
        for (int mi = 0; mi < 4; mi++) af0[mi] = *(const bf16x8*)(aU0 + mi * 2048 + psA);
#pragma unroll
        for (int ni = 0; ni < 4; ni++) bf0[ni] = *(const bf16x8*)(bRb + ni * 2048 + psA);
#pragma unroll
        for (int mi = 0; mi < 4; mi++) af1[mi] = *(const bf16x8*)(aU1 + mi * 2048 + psA);
        if (t + 1 < NT2) stage_B(t + 1, 0, nb);
        LGKMW(4); SB0();
        PRIO(1);
#pragma unroll
        for (int mi = 0; mi < 4; mi++)
#pragma unroll
            for (int ni = 0; ni < 4; ni++)
                acc[mi][ni] = __builtin_amdgcn_mfma_f32_16x16x32_bf16(af0[mi], bf0[ni], acc[mi][ni], 0, 0, 0);
        PRIO(0);

        // ---- P1: ahead reads af0(ksB), bf1(ksB); stage B-h1(t+1), A-m1(t+1); MFMA af1xbf0 ----
#pragma unroll
        for (int mi = 0; mi < 4; mi++) af0[mi] = *(const bf16x8*)(aU0 + mi * 2048 + psB);
#pragma unroll
        for (int ni = 0; ni < 4; ni++) bf1[ni] = *(const bf16x8*)(bRb + ni * 2048 + psB);
        if (t + 1 < NT2) { stage_B(t + 1, 1, nb); stage_Au(t + 1, 1, smem + 49152 + nb * 16384); }
        LGKMW(8); SB0();
        PRIO(1);
#pragma unroll
        for (int mi = 0; mi < 4; mi++)
#pragma unroll
            for (int ni = 0; ni < 4; ni++)
                acc[4 + mi][ni] = __builtin_amdgcn_mfma_f32_16x16x32_bf16(af1[mi], bf0[ni], acc[4 + mi][ni], 0, 0, 0);
        PRIO(0);

        // ---- P2: ahead read af1(ksB); MFMA af0xbf1 ----
#pragma unroll
        for (int mi = 0; mi < 4; mi++) af1[mi] = *(const bf16x8*)(aU1 + mi * 2048 + psB);
        LGKMW(4); SB0();
        PRIO(1);
#pragma unroll
        for (int mi = 0; mi < 4; mi++)
#pragma unroll
            for (int ni = 0; ni < 4; ni++)
                acc[mi][ni] = __builtin_amdgcn_mfma_f32_16x16x32_bf16(af0[mi], bf1[ni], acc[mi][ni], 0, 0, 0);
        PRIO(0);

        // ---- P3: stage A-m0(t+2) -> ring slot s2; MFMA af1xbf1 ----
        if (t + 2 < NT2) stage_Au(t + 2, 0, smem + s2 * 16384);
        LGKMW(0); SB0();
        PRIO(1);
#pragma unroll
        for (int mi = 0; mi < 4; mi++)
#pragma unroll
            for (int ni = 0; ni < 4; ni++)
                acc[4 + mi][ni] = __builtin_amdgcn_mfma_f32_16x16x32_bf16(af1[mi], bf1[ni], acc[4 + mi][ni], 0, 0, 0);
        PRIO(0);
        if (t < NT2 - 2) { VMCW(2); } else { VMCW(0); }
        BAR();

        s0 = s0 + 1; if (s0 >= 3) s0 -= 3;
    }

    // epilogue: C/D layout col = lane&15, row = (lane>>4)*4 + reg
    int wrow = m_base + wr * 128;
    int wcol = n_base + wc * 64;
    float bv[4];
    float4 lb0[4], lb1[4];
#pragma unroll
    for (int ni = 0; ni < 4; ni++) {
        int n = wcol + ni * 16 + l15;
        bv[ni] = bias[n];
        lb0[ni] = *(const float4*)(loraB + (size_t)n * 8);
        lb1[ni] = *(const float4*)(loraB + (size_t)n * 8 + 4);
    }
#pragma unroll
    for (int mi = 0; mi < 8; mi++) {
#pragma unroll
        for (int r = 0; r < 4; r++) {
            int m = wrow + mi * 16 + lhi * 4 + r;
            float4 xa0 = *(const float4*)(xa + (size_t)m * 8);
            float4 xa1 = *(const float4*)(xa + (size_t)m * 8 + 4);
#pragma unroll
            for (int ni = 0; ni < 4; ni++) {
                int n = wcol + ni * 16 + l15;
                float lora = xa0.x * lb0[ni].x + xa0.y * lb0[ni].y + xa0.z * lb0[ni].z + xa0.w * lb0[ni].w
                           + xa1.x * lb1[ni].x + xa1.y * lb1[ni].y + xa1.z * lb1[ni].z + xa1.w * lb1[ni].w;
                out[(size_t)m * N_DIM + n] = acc[mi][ni][r] + bv[ni] + lora;
            }
        }
    }
}

// ---------------- fallback (ws too small): correct but slow ----------------
__global__ void fallback_kernel(const float* __restrict__ x, const int* __restrict__ ids,
                                const float* __restrict__ W, const float* __restrict__ b,
                                const float* __restrict__ A, const float* __restrict__ B8,
                                float* __restrict__ out) {
    __shared__ float xs[K_DIM];
    __shared__ float xa_s[8];
    int row = blockIdx.y;
    int t = threadIdx.x;
    const float* xr = x + (size_t)row * K_DIM;
    for (int k = t; k < K_DIM; k += 256) xs[k] = xr[k];
    __syncthreads();
    if (t < 8) {
        float s = 0.f;
        for (int k = 0; k < K_DIM; k++) s += xs[k] * A[t * K_DIM + k];
        xa_s[t] = (ids[row] == 7) ? s * 2.0f : 0.0f;
    }
    __syncthreads();
    int col = blockIdx.x * 256 + t;
    const float* wr = W + (size_t)col * K_DIM;
    float acc = 0.f;
    for (int k = 0; k < K_DIM; k++) acc += xs[k] * wr[k];
    float lora = 0.f;
#pragma unroll
    for (int rr = 0; rr < 8; rr++) lora += xa_s[rr] * B8[col * 8 + rr];
    out[(size_t)row * N_DIM + col] = acc + b[col] + lora;
}

extern "C" void kernel_launch(void* const* d_in, const int* in_sizes, int n_in,
                              void* d_out, int out_size, void* d_ws, size_t ws_size,
                              hipStream_t stream) {
    const float* x   = (const float*)d_in[0];
    const int*   ids = (const int*)d_in[1];
    const float* W   = (const float*)d_in[2];
    const float* b   = (const float*)d_in[3];
    const float* lA  = (const float*)d_in[4];
    const float* lB  = (const float*)d_in[5];
    float* out = (float*)d_out;

    size_t wb_bytes = (size_t)N_DIM * K_DIM * 2;          // 32 MiB
    size_t xb_bytes = (size_t)M_DIM * K_DIM * 2;          // 128 MiB
    size_t xa_bytes = (size_t)M_DIM * 8 * 4;              // 0.5 MiB
    size_t ab_bytes = (size_t)8 * K_DIM * 2;              // 64 KiB

    if (ws_size >= wb_bytes + xb_bytes + xa_bytes + ab_bytes) {
        __hip_bfloat16* Wb  = (__hip_bfloat16*)d_ws;
        __hip_bfloat16* Xb  = (__hip_bfloat16*)((char*)d_ws + wb_bytes);
        float*          xav = (float*)((char*)d_ws + wb_bytes + xb_bytes);
        __hip_bfloat16* Abf = (__hip_bfloat16*)((char*)d_ws + wb_bytes + xb_bytes + xa_bytes);

        cvt_wa<<<1024 + 16, 256, 0, stream>>>(W, Wb, lA, Abf);
        cvt_x_xa<<<M_DIM / 8, 256, 0, stream>>>(x, ids, Abf, Xb, xav);
        gemm_bias_lora<<<(M_DIM / BM) * (N_DIM / BN), 512, 0, stream>>>(Xb, Wb, b, xav, lB, out);
    } else {
        fallback_kernel<<<dim3(N_DIM / 256, M_DIM), 256, 0, stream>>>(x, ids, W, b, lA, lB, out);
    }
}